// Round 3
// baseline (800.373 us; speedup 1.0000x reference)
//
#include <hip/hip_runtime.h>
#include <math.h>

#define B_ 16
#define HB 8             // batches per group (2 groups)
#define C_ 512
#define H_ 56
#define W_ 56
#define N_ 3136          // H_*W_
#define NH 8
#define HD 64
#define SPLIT 7          // n-split for gram; 3136/7 = 448
#define PV_TILES 13      // ceil(3136/256)

typedef unsigned short bf16;

__device__ inline float bf2f(unsigned short u) {
    union { unsigned int i; float f; } v; v.i = ((unsigned int)u) << 16; return v.f;
}
__device__ inline unsigned short f2bf(float f) {
    union { float f; unsigned int i; } v; v.f = f;
    unsigned int r = v.i + 0x7fffu + ((v.i >> 16) & 1u);
    return (unsigned short)(r >> 16);
}

// ---------------------------------------------------------------------------
// Depthwise 3x3 conv + BN. wmask bit0: write q,k -> qkdst[(b_l*2+s)*C+c][n].
// wmask bit1: write v -> vdst[b_l*C+c][n]. All bf16.
// ---------------------------------------------------------------------------
__global__ __launch_bounds__(256) void conv_bn_kernel(
    const float* __restrict__ x, const float* __restrict__ cw,
    const float* __restrict__ gamma, const float* __restrict__ beta,
    const float* __restrict__ mean, const float* __restrict__ var,
    bf16* __restrict__ qkdst, bf16* __restrict__ vdst, int b0, int wmask)
{
    int idx = blockIdx.x * 256 + threadIdx.x;   // over HB*C_*N_
    int n = idx % N_; int tmp = idx / N_;
    int ic = tmp % C_; int b_l = tmp / C_;
    int b = b0 + b_l;
    int yy = n / W_, xx = n % W_;
    const float* xin = x + ((size_t)b * C_ + ic) * N_;

    float vin[9];
#pragma unroll
    for (int ky = 0; ky < 3; ++ky) {
#pragma unroll
        for (int kx = 0; kx < 3; ++kx) {
            int y2 = yy + ky - 1, x2 = xx + kx - 1;
            bool ok = (y2 >= 0) && (y2 < H_) && (x2 >= 0) && (x2 < W_);
            vin[ky*3+kx] = ok ? xin[y2 * W_ + x2] : 0.f;
        }
    }
#pragma unroll
    for (int t = 0; t < 3; ++t) {
        int o = ic * 3 + t;                  // output channel in [0, 3C)
        int s = o >> 9;                      // 0=q 1=k 2=v
        int c = o & 511;
        bool doqk = (s < 2) && (wmask & 1);
        bool dov  = (s == 2) && (wmask & 2);
        if (doqk || dov) {
            const float* wp = cw + o * 9;
            float acc = 0.f;
#pragma unroll
            for (int k = 0; k < 9; ++k) acc = fmaf(vin[k], wp[k], acc);
            float inv = gamma[o] * rsqrtf(var[o] + 1e-5f);
            float bias = fmaf(-mean[o], inv, beta[o]);
            float r = fmaf(acc, inv, bias);
            if (doqk)
                qkdst[(((size_t)b_l * 2 + s) * C_ + c) * N_ + n] = f2bf(r);
            else
                vdst[((size_t)b_l * C_ + c) * N_ + n] = f2bf(r);
        }
    }
}

// ---------------------------------------------------------------------------
// Gram partials: part[s][b_l*NH+h][d*64+e] = sum_{n in split s} q[d,n]*k[e,n]
// ---------------------------------------------------------------------------
__global__ __launch_bounds__(256) void gram_kernel(
    const bf16* __restrict__ qk, float* __restrict__ part)
{
    int bid = blockIdx.x;                 // HB*NH*SPLIT
    int s = bid % SPLIT; int bh = bid / SPLIT;
    int h = bh % NH; int b_l = bh / NH;
    const bf16* qp = qk + (((size_t)b_l * 2 + 0) * C_ + h * HD) * N_;
    const bf16* kp = qk + (((size_t)b_l * 2 + 1) * C_ + h * HD) * N_;
    int n0 = s * (N_ / SPLIT);            // 448 per split

    __shared__ float qs[64][68];
    __shared__ float ks[64][68];
    int t = threadIdx.x;
    int d0 = (t >> 4) << 2;
    int e0 = (t & 15) << 2;
    float acc[4][4] = {};

    for (int nc = 0; nc < N_ / SPLIT; nc += 64) {
        __syncthreads();
#pragma unroll
        for (int r = 0; r < 4; ++r) {
            int slot = r * 256 + t;       // 0..1023
            int row = slot >> 4, c4 = (slot & 15) << 2;
            ushort4 uq = *(const ushort4*)(qp + (size_t)row * N_ + n0 + nc + c4);
            ushort4 uk = *(const ushort4*)(kp + (size_t)row * N_ + n0 + nc + c4);
            qs[row][c4+0] = bf2f(uq.x); qs[row][c4+1] = bf2f(uq.y);
            qs[row][c4+2] = bf2f(uq.z); qs[row][c4+3] = bf2f(uq.w);
            ks[row][c4+0] = bf2f(uk.x); ks[row][c4+1] = bf2f(uk.y);
            ks[row][c4+2] = bf2f(uk.z); ks[row][c4+3] = bf2f(uk.w);
        }
        __syncthreads();
#pragma unroll
        for (int nn = 0; nn < 64; nn += 4) {
            float4 qa[4], ka[4];
#pragma unroll
            for (int i = 0; i < 4; ++i) qa[i] = *(const float4*)&qs[d0+i][nn];
#pragma unroll
            for (int j = 0; j < 4; ++j) ka[j] = *(const float4*)&ks[e0+j][nn];
#pragma unroll
            for (int i = 0; i < 4; ++i)
#pragma unroll
                for (int j = 0; j < 4; ++j)
                    acc[i][j] += qa[i].x*ka[j].x + qa[i].y*ka[j].y
                               + qa[i].z*ka[j].z + qa[i].w*ka[j].w;
        }
    }
    float* pp = part + ((size_t)s * (HB*NH) + bh) * 4096;
#pragma unroll
    for (int i = 0; i < 4; ++i)
#pragma unroll
        for (int j = 0; j < 4; ++j)
            pp[(d0+i) * 64 + (e0+j)] = acc[i][j];
}

// ---------------------------------------------------------------------------
// Reduce partials, scale, softmax over e. One wave per (bh,d) row.
// ---------------------------------------------------------------------------
__global__ __launch_bounds__(64) void softmax_kernel(
    const float* __restrict__ part, float* __restrict__ P)
{
    int row = blockIdx.x;                 // bh*64 + d
    int e = threadIdx.x;
    size_t base = (size_t)row * 64 + e;
    float val = 0.f;
#pragma unroll
    for (int s = 0; s < SPLIT; ++s) val += part[(size_t)s * (HB*NH*4096) + base];
    val *= 0.125f;                        // hd^-0.5
    float m = val;
#pragma unroll
    for (int off = 32; off > 0; off >>= 1) m = fmaxf(m, __shfl_xor(m, off));
    float ex = expf(val - m);
    float sum = ex;
#pragma unroll
    for (int off = 32; off > 0; off >>= 1) sum += __shfl_xor(sum, off);
    P[base] = ex / sum;
}

// ---------------------------------------------------------------------------
// outA[b_l][d][h][n] = sum_e P[b_l,h,d,e] * v[b_l][h*64+e][n]   (bf16 out)
// Flat [d][h][n] order == reference's swapaxes(1,2).reshape(B,N,C) layout.
// ---------------------------------------------------------------------------
__global__ __launch_bounds__(256) void pv_kernel(
    const bf16* __restrict__ v, const float* __restrict__ P,
    bf16* __restrict__ outA)
{
    int bid = blockIdx.x;
    int tile = bid % PV_TILES; int bh = bid / PV_TILES;
    int h = bh % NH, b_l = bh / NH;
    __shared__ float Pt[64][68];          // Pt[e][d]
    int t = threadIdx.x;
#pragma unroll
    for (int r = 0; r < 16; ++r) {
        int j = r * 256 + t; int d = j >> 6, e = j & 63;
        Pt[e][d] = P[(size_t)bh * 4096 + j];
    }
    __syncthreads();
    int n = tile * 256 + t;
    if (n < N_) {
        const bf16* vp = v + ((size_t)b_l * C_ + h * HD) * N_ + n;
        float acc[64];
#pragma unroll
        for (int d = 0; d < 64; ++d) acc[d] = 0.f;
        for (int e = 0; e < 64; ++e) {
            float ve = bf2f(vp[(size_t)e * N_]);
            const float4* pr = (const float4*)&Pt[e][0];
#pragma unroll
            for (int d4 = 0; d4 < 16; ++d4) {
                float4 p = pr[d4];
                acc[d4*4+0] = fmaf(p.x, ve, acc[d4*4+0]);
                acc[d4*4+1] = fmaf(p.y, ve, acc[d4*4+1]);
                acc[d4*4+2] = fmaf(p.z, ve, acc[d4*4+2]);
                acc[d4*4+3] = fmaf(p.w, ve, acc[d4*4+3]);
            }
        }
        bf16* op = outA + (size_t)b_l * (C_*N_) + (size_t)h * N_ + n;
#pragma unroll
        for (int d = 0; d < 64; ++d) op[(size_t)d * (NH*N_)] = f2bf(acc[d]);
    }
}

// ---------------------------------------------------------------------------
// Projection: out[b0+b_l][co][n'] = sum_c' W[co][c'] * A[b_l][n'][c'] + pb[co]
// A = outA viewed as (N_, C_) row-major bf16 per batch. 64x64 tile, K-chunk 32.
// ---------------------------------------------------------------------------
__global__ __launch_bounds__(256) void proj_kernel(
    const bf16* __restrict__ A, const float* __restrict__ Wt,
    const float* __restrict__ bias, float* __restrict__ out, int b0)
{
    int bid = blockIdx.x;                 // HB * 8 * 49
    int nt = bid % 49; int tmp = bid / 49;
    int mt = tmp % 8; int b_l = tmp / 8;
    int t = threadIdx.x;
    int m0 = mt * 64, n0 = nt * 64;
    __shared__ float As[32][68];          // As[kk][nn]
    __shared__ float Ws[32][68];          // Ws[kk][mm]
    int mm0 = (t >> 4) << 2, nn0 = (t & 15) << 2;
    float acc[4][4] = {};
    const bf16* Ab = A + (size_t)b_l * (N_ * C_);

    for (int k0 = 0; k0 < C_; k0 += 32) {
        __syncthreads();
#pragma unroll
        for (int r = 0; r < 8; ++r) {
            int j = r * 256 + t;          // 0..2047
            int rr = j >> 5, kk = j & 31;
            Ws[kk][rr] = Wt[(size_t)(m0 + rr) * C_ + k0 + kk];
        }
#pragma unroll
        for (int r = 0; r < 4; ++r) {
            int j = r * 256 + t;          // 0..1023
            int rr = j >> 4, kk2 = (j & 15) << 1;
            ushort2 ua = *(const ushort2*)(Ab + (size_t)(n0 + rr) * C_ + k0 + kk2);
            As[kk2+0][rr] = bf2f(ua.x);
            As[kk2+1][rr] = bf2f(ua.y);
        }
        __syncthreads();
#pragma unroll
        for (int kk = 0; kk < 32; ++kk) {
            float4 av = *(const float4*)&As[kk][nn0];
            float4 wv = *(const float4*)&Ws[kk][mm0];
            float a4[4] = {av.x, av.y, av.z, av.w};
            float w4[4] = {wv.x, wv.y, wv.z, wv.w};
#pragma unroll
            for (int i = 0; i < 4; ++i)
#pragma unroll
                for (int j2 = 0; j2 < 4; ++j2)
                    acc[i][j2] = fmaf(w4[i], a4[j2], acc[i][j2]);
        }
    }
    float* ob = out + (((size_t)(b0 + b_l) * C_) + m0) * N_ + n0;
#pragma unroll
    for (int i = 0; i < 4; ++i) {
        float bi = bias[m0 + mm0 + i];
        float4 r;
        r.x = acc[i][0] + bi; r.y = acc[i][1] + bi;
        r.z = acc[i][2] + bi; r.w = acc[i][3] + bi;
        *(float4*)&ob[(size_t)(mm0 + i) * N_ + nn0] = r;
    }
}

extern "C" void kernel_launch(void* const* d_in, const int* in_sizes, int n_in,
                              void* d_out, int out_size, void* d_ws, size_t ws_size,
                              hipStream_t stream) {
    const float* x     = (const float*)d_in[0];
    const float* cw    = (const float*)d_in[1];
    const float* gamma = (const float*)d_in[2];
    const float* beta  = (const float*)d_in[3];
    const float* mean  = (const float*)d_in[4];
    const float* var   = (const float*)d_in[5];
    const float* pw    = (const float*)d_in[6];
    const float* pb    = (const float*)d_in[7];
    float* out = (float*)d_out;

    const size_t QK_B   = (size_t)HB * 2 * C_ * N_ * sizeof(bf16);  // 51,380,224
    const size_t V_B    = (size_t)HB * C_ * N_ * sizeof(bf16);      // 25,690,112
    const size_t PART_B = (size_t)SPLIT * HB * NH * 4096 * 4;       //  7,340,032
    const size_t P_B    = (size_t)HB * NH * 4096 * 4;               //  1,048,576
    char* wsp = (char*)d_ws;
    bool fast = ws_size >= QK_B + V_B + PART_B + P_B;               // 85.5 MB

    for (int g = 0; g < 2; ++g) {
        int b0 = g * HB;
        if (fast) {
            bf16*  qk   = (bf16*)wsp;
            bf16*  v    = (bf16*)(wsp + QK_B);
            float* part = (float*)(wsp + QK_B + V_B);
            float* P    = (float*)(wsp + QK_B + V_B + PART_B);
            bf16*  outA = qk;   // reuse q,k region after gram
            conv_bn_kernel<<<(HB * C_ * N_) / 256, 256, 0, stream>>>(
                x, cw, gamma, beta, mean, var, qk, v, b0, 3);
            gram_kernel<<<HB * NH * SPLIT, 256, 0, stream>>>(qk, part);
            softmax_kernel<<<HB * NH * 64, 64, 0, stream>>>(part, P);
            pv_kernel<<<HB * NH * PV_TILES, 256, 0, stream>>>(v, P, outA);
            proj_kernel<<<HB * 8 * 49, 256, 0, stream>>>(outA, pw, pb, out, b0);
        } else {
            bf16*  qk   = (bf16*)wsp;
            float* part = (float*)(wsp + QK_B);
            float* P    = (float*)(wsp + QK_B + PART_B);
            bf16*  v    = qk;                       // reuse after gram
            bf16*  outA = (bf16*)(wsp + V_B);       // second half of qk region
            conv_bn_kernel<<<(HB * C_ * N_) / 256, 256, 0, stream>>>(
                x, cw, gamma, beta, mean, var, qk, (bf16*)nullptr, b0, 1);
            gram_kernel<<<HB * NH * SPLIT, 256, 0, stream>>>(qk, part);
            softmax_kernel<<<HB * NH * 64, 64, 0, stream>>>(part, P);
            conv_bn_kernel<<<(HB * C_ * N_) / 256, 256, 0, stream>>>(
                x, cw, gamma, beta, mean, var, (bf16*)nullptr, v, b0, 2);
            pv_kernel<<<HB * NH * PV_TILES, 256, 0, stream>>>(v, P, outA);
            proj_kernel<<<HB * 8 * 49, 256, 0, stream>>>(outA, pw, pb, out, b0);
        }
    }
}

// Round 4
// 668.838 us; speedup vs baseline: 1.1967x; 1.1967x over previous
//
#include <hip/hip_runtime.h>
#include <math.h>

#define B_ 16
#define HB 8             // batches per group (2 groups)
#define C_ 512
#define H_ 56
#define W_ 56
#define N_ 3136          // H_*W_
#define NH 8
#define HD 64
#define SPLIT 7          // n-split for gram; 3136/7 = 448
#define PV_TILES 13      // ceil(3136/256)

typedef unsigned short bf16;
typedef __attribute__((ext_vector_type(8))) short short8;
typedef __attribute__((ext_vector_type(4))) float f32x4;

__device__ inline float bf2f(unsigned short u) {
    union { unsigned int i; float f; } v; v.i = ((unsigned int)u) << 16; return v.f;
}
__device__ inline unsigned short f2bf(float f) {
    union { float f; unsigned int i; } v; v.f = f;
    unsigned int r = v.i + 0x7fffu + ((v.i >> 16) & 1u);
    return (unsigned short)(r >> 16);
}

// ---------------------------------------------------------------------------
// Depthwise 3x3 conv + BN. wmask bit0: write q,k -> qkdst[(b_l*2+s)*C+c][n].
// wmask bit1: write v -> vdst[b_l*C+c][n]. All bf16.
// ---------------------------------------------------------------------------
__global__ __launch_bounds__(256) void conv_bn_kernel(
    const float* __restrict__ x, const float* __restrict__ cw,
    const float* __restrict__ gamma, const float* __restrict__ beta,
    const float* __restrict__ mean, const float* __restrict__ var,
    bf16* __restrict__ qkdst, bf16* __restrict__ vdst, int b0, int wmask)
{
    int idx = blockIdx.x * 256 + threadIdx.x;   // over HB*C_*N_
    int n = idx % N_; int tmp = idx / N_;
    int ic = tmp % C_; int b_l = tmp / C_;
    int b = b0 + b_l;
    int yy = n / W_, xx = n % W_;
    const float* xin = x + ((size_t)b * C_ + ic) * N_;

    float vin[9];
#pragma unroll
    for (int ky = 0; ky < 3; ++ky) {
#pragma unroll
        for (int kx = 0; kx < 3; ++kx) {
            int y2 = yy + ky - 1, x2 = xx + kx - 1;
            bool ok = (y2 >= 0) && (y2 < H_) && (x2 >= 0) && (x2 < W_);
            vin[ky*3+kx] = ok ? xin[y2 * W_ + x2] : 0.f;
        }
    }
#pragma unroll
    for (int t = 0; t < 3; ++t) {
        int o = ic * 3 + t;                  // output channel in [0, 3C)
        int s = o >> 9;                      // 0=q 1=k 2=v
        int c = o & 511;
        bool doqk = (s < 2) && (wmask & 1);
        bool dov  = (s == 2) && (wmask & 2);
        if (doqk || dov) {
            const float* wp = cw + o * 9;
            float acc = 0.f;
#pragma unroll
            for (int k = 0; k < 9; ++k) acc = fmaf(vin[k], wp[k], acc);
            float inv = gamma[o] * rsqrtf(var[o] + 1e-5f);
            float bias = fmaf(-mean[o], inv, beta[o]);
            float r = fmaf(acc, inv, bias);
            if (doqk)
                qkdst[(((size_t)b_l * 2 + s) * C_ + c) * N_ + n] = f2bf(r);
            else
                vdst[((size_t)b_l * C_ + c) * N_ + n] = f2bf(r);
        }
    }
}

// ---------------------------------------------------------------------------
// Gram partials: part[s][b_l*NH+h][d*64+e] = sum_{n in split s} q[d,n]*k[e,n]
// ---------------------------------------------------------------------------
__global__ __launch_bounds__(256) void gram_kernel(
    const bf16* __restrict__ qk, float* __restrict__ part)
{
    int bid = blockIdx.x;                 // HB*NH*SPLIT
    int s = bid % SPLIT; int bh = bid / SPLIT;
    int h = bh % NH; int b_l = bh / NH;
    const bf16* qp = qk + (((size_t)b_l * 2 + 0) * C_ + h * HD) * N_;
    const bf16* kp = qk + (((size_t)b_l * 2 + 1) * C_ + h * HD) * N_;
    int n0 = s * (N_ / SPLIT);            // 448 per split

    __shared__ float qs[64][68];
    __shared__ float ks[64][68];
    int t = threadIdx.x;
    int d0 = (t >> 4) << 2;
    int e0 = (t & 15) << 2;
    float acc[4][4] = {};

    for (int nc = 0; nc < N_ / SPLIT; nc += 64) {
        __syncthreads();
#pragma unroll
        for (int r = 0; r < 4; ++r) {
            int slot = r * 256 + t;       // 0..1023
            int row = slot >> 4, c4 = (slot & 15) << 2;
            ushort4 uq = *(const ushort4*)(qp + (size_t)row * N_ + n0 + nc + c4);
            ushort4 uk = *(const ushort4*)(kp + (size_t)row * N_ + n0 + nc + c4);
            qs[row][c4+0] = bf2f(uq.x); qs[row][c4+1] = bf2f(uq.y);
            qs[row][c4+2] = bf2f(uq.z); qs[row][c4+3] = bf2f(uq.w);
            ks[row][c4+0] = bf2f(uk.x); ks[row][c4+1] = bf2f(uk.y);
            ks[row][c4+2] = bf2f(uk.z); ks[row][c4+3] = bf2f(uk.w);
        }
        __syncthreads();
#pragma unroll
        for (int nn = 0; nn < 64; nn += 4) {
            float4 qa[4], ka[4];
#pragma unroll
            for (int i = 0; i < 4; ++i) qa[i] = *(const float4*)&qs[d0+i][nn];
#pragma unroll
            for (int j = 0; j < 4; ++j) ka[j] = *(const float4*)&ks[e0+j][nn];
#pragma unroll
            for (int i = 0; i < 4; ++i)
#pragma unroll
                for (int j = 0; j < 4; ++j)
                    acc[i][j] += qa[i].x*ka[j].x + qa[i].y*ka[j].y
                               + qa[i].z*ka[j].z + qa[i].w*ka[j].w;
        }
    }
    float* pp = part + ((size_t)s * (HB*NH) + bh) * 4096;
#pragma unroll
    for (int i = 0; i < 4; ++i)
#pragma unroll
        for (int j = 0; j < 4; ++j)
            pp[(d0+i) * 64 + (e0+j)] = acc[i][j];
}

// ---------------------------------------------------------------------------
// Reduce partials, scale, softmax over e. One wave per (bh,d) row.
// ---------------------------------------------------------------------------
__global__ __launch_bounds__(64) void softmax_kernel(
    const float* __restrict__ part, float* __restrict__ P)
{
    int row = blockIdx.x;                 // bh*64 + d
    int e = threadIdx.x;
    size_t base = (size_t)row * 64 + e;
    float val = 0.f;
#pragma unroll
    for (int s = 0; s < SPLIT; ++s) val += part[(size_t)s * (HB*NH*4096) + base];
    val *= 0.125f;                        // hd^-0.5
    float m = val;
#pragma unroll
    for (int off = 32; off > 0; off >>= 1) m = fmaxf(m, __shfl_xor(m, off));
    float ex = expf(val - m);
    float sum = ex;
#pragma unroll
    for (int off = 32; off > 0; off >>= 1) sum += __shfl_xor(sum, off);
    P[base] = ex / sum;
}

// ---------------------------------------------------------------------------
// outA[b_l][d][h][n] = sum_e P[b_l,h,d,e] * v[b_l][h*64+e][n]   (bf16 out)
// Flat [d][h][n] order == reference's swapaxes(1,2).reshape(B,N,C) layout.
// ---------------------------------------------------------------------------
__global__ __launch_bounds__(256) void pv_kernel(
    const bf16* __restrict__ v, const float* __restrict__ P,
    bf16* __restrict__ outA)
{
    int bid = blockIdx.x;
    int tile = bid % PV_TILES; int bh = bid / PV_TILES;
    int h = bh % NH, b_l = bh / NH;
    __shared__ float Pt[64][68];          // Pt[e][d]
    int t = threadIdx.x;
#pragma unroll
    for (int r = 0; r < 16; ++r) {
        int j = r * 256 + t; int d = j >> 6, e = j & 63;
        Pt[e][d] = P[(size_t)bh * 4096 + j];
    }
    __syncthreads();
    int n = tile * 256 + t;
    if (n < N_) {
        const bf16* vp = v + ((size_t)b_l * C_ + h * HD) * N_ + n;
        float acc[64];
#pragma unroll
        for (int d = 0; d < 64; ++d) acc[d] = 0.f;
        for (int e = 0; e < 64; ++e) {
            float ve = bf2f(vp[(size_t)e * N_]);
            const float4* pr = (const float4*)&Pt[e][0];
#pragma unroll
            for (int d4 = 0; d4 < 16; ++d4) {
                float4 p = pr[d4];
                acc[d4*4+0] = fmaf(p.x, ve, acc[d4*4+0]);
                acc[d4*4+1] = fmaf(p.y, ve, acc[d4*4+1]);
                acc[d4*4+2] = fmaf(p.z, ve, acc[d4*4+2]);
                acc[d4*4+3] = fmaf(p.w, ve, acc[d4*4+3]);
            }
        }
        bf16* op = outA + (size_t)b_l * (C_*N_) + (size_t)h * N_ + n;
#pragma unroll
        for (int d = 0; d < 64; ++d) op[(size_t)d * (NH*N_)] = f2bf(acc[d]);
    }
}

// ---------------------------------------------------------------------------
// Convert projection weights f32 -> bf16 (512x512).
// ---------------------------------------------------------------------------
__global__ __launch_bounds__(256) void wconv_kernel(
    const float* __restrict__ w, bf16* __restrict__ wb)
{
    int i = blockIdx.x * 256 + threadIdx.x;   // 262144 total
    wb[i] = f2bf(w[i]);
}

// ---------------------------------------------------------------------------
// MFMA projection: out[b0+b_l][co][n] = sum_c Wb[co][c]*A[b_l][n][c] + pb[co]
// A is (N_, C_) bf16 row-major per batch; Wb is (C_, C_) bf16.
// Block = 4 waves, tile 128(co) x 64(n); wave w owns n-cols [w*16, w*16+16).
// Fragments load directly from global (16B contiguous along K per lane).
// ---------------------------------------------------------------------------
__global__ __launch_bounds__(256) void proj_mfma_kernel(
    const bf16* __restrict__ A, const bf16* __restrict__ Wb,
    const float* __restrict__ bias, float* __restrict__ out, int b0)
{
    int bid = blockIdx.x;                 // HB * 4 * 49
    int nt = bid % 49; int tmp = bid / 49;
    int mt = tmp % 4; int b_l = tmp / 4;
    int wave = threadIdx.x >> 6;
    int lane = threadIdx.x & 63;
    int m0 = mt * 128;
    int n0 = nt * 64 + wave * 16;
    int r16 = lane & 15;                  // row-within-16 for A/B frags
    int kg = lane >> 4;                   // k-group 0..3 (8 bf16 each)
    const bf16* Ab = A + (size_t)b_l * N_ * C_;
    const bf16* arow = Ab + (size_t)(n0 + r16) * C_ + kg * 8;

    f32x4 acc[8];
#pragma unroll
    for (int i = 0; i < 8; ++i) acc[i] = (f32x4){0.f, 0.f, 0.f, 0.f};

    for (int k0 = 0; k0 < C_; k0 += 32) {
        short8 bfrag = *(const short8*)(arow + k0);
#pragma unroll
        for (int mi = 0; mi < 8; ++mi) {
            short8 afrag = *(const short8*)(Wb + (size_t)(m0 + mi*16 + r16) * C_ + k0 + kg*8);
            acc[mi] = __builtin_amdgcn_mfma_f32_16x16x32_bf16(afrag, bfrag, acc[mi], 0, 0, 0);
        }
    }
    // D layout: col = lane&15 (n), row = (lane>>4)*4 + reg (co within 16)
    float* ob = out + ((size_t)(b0 + b_l) * C_) * N_ + n0 + r16;
#pragma unroll
    for (int mi = 0; mi < 8; ++mi) {
        int cobase = m0 + mi*16 + kg*4;
#pragma unroll
        for (int r = 0; r < 4; ++r) {
            int co = cobase + r;
            ob[(size_t)co * N_] = acc[mi][r] + bias[co];
        }
    }
}

extern "C" void kernel_launch(void* const* d_in, const int* in_sizes, int n_in,
                              void* d_out, int out_size, void* d_ws, size_t ws_size,
                              hipStream_t stream) {
    const float* x     = (const float*)d_in[0];
    const float* cw    = (const float*)d_in[1];
    const float* gamma = (const float*)d_in[2];
    const float* beta  = (const float*)d_in[3];
    const float* mean  = (const float*)d_in[4];
    const float* var   = (const float*)d_in[5];
    const float* pw    = (const float*)d_in[6];
    const float* pb    = (const float*)d_in[7];
    float* out = (float*)d_out;

    const size_t QK_B   = (size_t)HB * 2 * C_ * N_ * sizeof(bf16);  // 51,380,224
    const size_t V_B    = (size_t)HB * C_ * N_ * sizeof(bf16);      // 25,690,112
    const size_t PART_B = (size_t)SPLIT * HB * NH * 4096 * 4;       //  7,340,032
    const size_t P_B    = (size_t)HB * NH * 4096 * 4;               //  1,048,576
    const size_t W_B    = (size_t)C_ * C_ * sizeof(bf16);           //    524,288
    char* wsp = (char*)d_ws;
    bool fast = ws_size >= QK_B + V_B + PART_B + P_B + W_B;         // 86.0 MB

    bf16* Wbf = fast ? (bf16*)(wsp + QK_B + V_B + PART_B + P_B)
                     : (bf16*)(wsp + QK_B + PART_B + P_B);
    wconv_kernel<<<(C_ * C_) / 256, 256, 0, stream>>>(pw, Wbf);

    for (int g = 0; g < 2; ++g) {
        int b0 = g * HB;
        if (fast) {
            bf16*  qk   = (bf16*)wsp;
            bf16*  v    = (bf16*)(wsp + QK_B);
            float* part = (float*)(wsp + QK_B + V_B);
            float* P    = (float*)(wsp + QK_B + V_B + PART_B);
            bf16*  outA = qk;   // reuse q,k region after gram
            conv_bn_kernel<<<(HB * C_ * N_) / 256, 256, 0, stream>>>(
                x, cw, gamma, beta, mean, var, qk, v, b0, 3);
            gram_kernel<<<HB * NH * SPLIT, 256, 0, stream>>>(qk, part);
            softmax_kernel<<<HB * NH * 64, 64, 0, stream>>>(part, P);
            pv_kernel<<<HB * NH * PV_TILES, 256, 0, stream>>>(v, P, outA);
            proj_mfma_kernel<<<HB * 4 * 49, 256, 0, stream>>>(outA, Wbf, pb, out, b0);
        } else {
            bf16*  qk   = (bf16*)wsp;
            float* part = (float*)(wsp + QK_B);
            float* P    = (float*)(wsp + QK_B + PART_B);
            bf16*  v    = qk;                       // reuse after gram
            bf16*  outA = (bf16*)(wsp + V_B);       // second half of qk region
            conv_bn_kernel<<<(HB * C_ * N_) / 256, 256, 0, stream>>>(
                x, cw, gamma, beta, mean, var, qk, (bf16*)nullptr, b0, 1);
            gram_kernel<<<HB * NH * SPLIT, 256, 0, stream>>>(qk, part);
            softmax_kernel<<<HB * NH * 64, 64, 0, stream>>>(part, P);
            conv_bn_kernel<<<(HB * C_ * N_) / 256, 256, 0, stream>>>(
                x, cw, gamma, beta, mean, var, (bf16*)nullptr, v, b0, 2);
            pv_kernel<<<HB * NH * PV_TILES, 256, 0, stream>>>(v, P, outA);
            proj_mfma_kernel<<<HB * 4 * 49, 256, 0, stream>>>(outA, Wbf, pb, out, b0);
        }
    }
}

// Round 5
// 512.557 us; speedup vs baseline: 1.5615x; 1.3049x over previous
//
#include <hip/hip_runtime.h>
#include <math.h>

#define B_ 16
#define HB 8             // batches per group (2 groups)
#define C_ 512
#define H_ 56
#define W_ 56
#define N_ 3136          // H_*W_
#define NH 8
#define HD 64
#define SPLIT 7          // n-split for gram; 3136/7 = 448
#define PV_TILES 13      // ceil(3136/256)

typedef unsigned short bf16;
typedef __attribute__((ext_vector_type(8))) short short8;
typedef __attribute__((ext_vector_type(4))) float f32x4;

__device__ inline float bf2f(unsigned short u) {
    union { unsigned int i; float f; } v; v.i = ((unsigned int)u) << 16; return v.f;
}
__device__ inline unsigned short f2bf(float f) {
    union { float f; unsigned int i; } v; v.f = f;
    unsigned int r = v.i + 0x7fffu + ((v.i >> 16) & 1u);
    return (unsigned short)(r >> 16);
}

// async global->LDS, 16B per lane, linear dest (wave-uniform base + lane*16)
__device__ inline void load_lds16(const bf16* g, void* l) {
    __builtin_amdgcn_global_load_lds(
        (const __attribute__((address_space(1))) void*)g,
        (__attribute__((address_space(3))) void*)l, 16, 0, 0);
}

// ---------------------------------------------------------------------------
// Depthwise 3x3 conv + BN. wmask bit0: write q,k -> qkdst[(b_l*2+s)*C+c][n].
// wmask bit1: write v -> vdst[b_l*C+c][n]. All bf16.
// ---------------------------------------------------------------------------
__global__ __launch_bounds__(256) void conv_bn_kernel(
    const float* __restrict__ x, const float* __restrict__ cw,
    const float* __restrict__ gamma, const float* __restrict__ beta,
    const float* __restrict__ mean, const float* __restrict__ var,
    bf16* __restrict__ qkdst, bf16* __restrict__ vdst, int b0, int wmask)
{
    int idx = blockIdx.x * 256 + threadIdx.x;   // over HB*C_*N_
    int n = idx % N_; int tmp = idx / N_;
    int ic = tmp % C_; int b_l = tmp / C_;
    int b = b0 + b_l;
    int yy = n / W_, xx = n % W_;
    const float* xin = x + ((size_t)b * C_ + ic) * N_;

    float vin[9];
#pragma unroll
    for (int ky = 0; ky < 3; ++ky) {
#pragma unroll
        for (int kx = 0; kx < 3; ++kx) {
            int y2 = yy + ky - 1, x2 = xx + kx - 1;
            bool ok = (y2 >= 0) && (y2 < H_) && (x2 >= 0) && (x2 < W_);
            vin[ky*3+kx] = ok ? xin[y2 * W_ + x2] : 0.f;
        }
    }
#pragma unroll
    for (int t = 0; t < 3; ++t) {
        int o = ic * 3 + t;                  // output channel in [0, 3C)
        int s = o >> 9;                      // 0=q 1=k 2=v
        int c = o & 511;
        bool doqk = (s < 2) && (wmask & 1);
        bool dov  = (s == 2) && (wmask & 2);
        if (doqk || dov) {
            const float* wp = cw + o * 9;
            float acc = 0.f;
#pragma unroll
            for (int k = 0; k < 9; ++k) acc = fmaf(vin[k], wp[k], acc);
            float inv = gamma[o] * rsqrtf(var[o] + 1e-5f);
            float bias = fmaf(-mean[o], inv, beta[o]);
            float r = fmaf(acc, inv, bias);
            if (doqk)
                qkdst[(((size_t)b_l * 2 + s) * C_ + c) * N_ + n] = f2bf(r);
            else
                vdst[((size_t)b_l * C_ + c) * N_ + n] = f2bf(r);
        }
    }
}

// ---------------------------------------------------------------------------
// Gram partials: part[s][b_l*NH+h][d*64+e] = sum_{n in split s} q[d,n]*k[e,n]
// ---------------------------------------------------------------------------
__global__ __launch_bounds__(256) void gram_kernel(
    const bf16* __restrict__ qk, float* __restrict__ part)
{
    int bid = blockIdx.x;                 // HB*NH*SPLIT
    int s = bid % SPLIT; int bh = bid / SPLIT;
    int h = bh % NH; int b_l = bh / NH;
    const bf16* qp = qk + (((size_t)b_l * 2 + 0) * C_ + h * HD) * N_;
    const bf16* kp = qk + (((size_t)b_l * 2 + 1) * C_ + h * HD) * N_;
    int n0 = s * (N_ / SPLIT);            // 448 per split

    __shared__ float qs[64][68];
    __shared__ float ks[64][68];
    int t = threadIdx.x;
    int d0 = (t >> 4) << 2;
    int e0 = (t & 15) << 2;
    float acc[4][4] = {};

    for (int nc = 0; nc < N_ / SPLIT; nc += 64) {
        __syncthreads();
#pragma unroll
        for (int r = 0; r < 4; ++r) {
            int slot = r * 256 + t;       // 0..1023
            int row = slot >> 4, c4 = (slot & 15) << 2;
            ushort4 uq = *(const ushort4*)(qp + (size_t)row * N_ + n0 + nc + c4);
            ushort4 uk = *(const ushort4*)(kp + (size_t)row * N_ + n0 + nc + c4);
            qs[row][c4+0] = bf2f(uq.x); qs[row][c4+1] = bf2f(uq.y);
            qs[row][c4+2] = bf2f(uq.z); qs[row][c4+3] = bf2f(uq.w);
            ks[row][c4+0] = bf2f(uk.x); ks[row][c4+1] = bf2f(uk.y);
            ks[row][c4+2] = bf2f(uk.z); ks[row][c4+3] = bf2f(uk.w);
        }
        __syncthreads();
#pragma unroll
        for (int nn = 0; nn < 64; nn += 4) {
            float4 qa[4], ka[4];
#pragma unroll
            for (int i = 0; i < 4; ++i) qa[i] = *(const float4*)&qs[d0+i][nn];
#pragma unroll
            for (int j = 0; j < 4; ++j) ka[j] = *(const float4*)&ks[e0+j][nn];
#pragma unroll
            for (int i = 0; i < 4; ++i)
#pragma unroll
                for (int j = 0; j < 4; ++j)
                    acc[i][j] += qa[i].x*ka[j].x + qa[i].y*ka[j].y
                               + qa[i].z*ka[j].z + qa[i].w*ka[j].w;
        }
    }
    float* pp = part + ((size_t)s * (HB*NH) + bh) * 4096;
#pragma unroll
    for (int i = 0; i < 4; ++i)
#pragma unroll
        for (int j = 0; j < 4; ++j)
            pp[(d0+i) * 64 + (e0+j)] = acc[i][j];
}

// ---------------------------------------------------------------------------
// Reduce partials, scale, softmax over e. One wave per (bh,d) row.
// ---------------------------------------------------------------------------
__global__ __launch_bounds__(64) void softmax_kernel(
    const float* __restrict__ part, float* __restrict__ P)
{
    int row = blockIdx.x;                 // bh*64 + d
    int e = threadIdx.x;
    size_t base = (size_t)row * 64 + e;
    float val = 0.f;
#pragma unroll
    for (int s = 0; s < SPLIT; ++s) val += part[(size_t)s * (HB*NH*4096) + base];
    val *= 0.125f;                        // hd^-0.5
    float m = val;
#pragma unroll
    for (int off = 32; off > 0; off >>= 1) m = fmaxf(m, __shfl_xor(m, off));
    float ex = expf(val - m);
    float sum = ex;
#pragma unroll
    for (int off = 32; off > 0; off >>= 1) sum += __shfl_xor(sum, off);
    P[base] = ex / sum;
}

// ---------------------------------------------------------------------------
// outA[b_l][d][h][n] = sum_e P[b_l,h,d,e] * v[b_l][h*64+e][n]   (bf16 out)
// Flat [d][h][n] order == reference's swapaxes(1,2).reshape(B,N,C) layout.
// ---------------------------------------------------------------------------
__global__ __launch_bounds__(256) void pv_kernel(
    const bf16* __restrict__ v, const float* __restrict__ P,
    bf16* __restrict__ outA)
{
    int bid = blockIdx.x;
    int tile = bid % PV_TILES; int bh = bid / PV_TILES;
    int h = bh % NH, b_l = bh / NH;
    __shared__ float Pt[64][68];          // Pt[e][d]
    int t = threadIdx.x;
#pragma unroll
    for (int r = 0; r < 16; ++r) {
        int j = r * 256 + t; int d = j >> 6, e = j & 63;
        Pt[e][d] = P[(size_t)bh * 4096 + j];
    }
    __syncthreads();
    int n = tile * 256 + t;
    if (n < N_) {
        const bf16* vp = v + ((size_t)b_l * C_ + h * HD) * N_ + n;
        float acc[64];
#pragma unroll
        for (int d = 0; d < 64; ++d) acc[d] = 0.f;
        for (int e = 0; e < 64; ++e) {
            float ve = bf2f(vp[(size_t)e * N_]);
            const float4* pr = (const float4*)&Pt[e][0];
#pragma unroll
            for (int d4 = 0; d4 < 16; ++d4) {
                float4 p = pr[d4];
                acc[d4*4+0] = fmaf(p.x, ve, acc[d4*4+0]);
                acc[d4*4+1] = fmaf(p.y, ve, acc[d4*4+1]);
                acc[d4*4+2] = fmaf(p.z, ve, acc[d4*4+2]);
                acc[d4*4+3] = fmaf(p.w, ve, acc[d4*4+3]);
            }
        }
        bf16* op = outA + (size_t)b_l * (C_*N_) + (size_t)h * N_ + n;
#pragma unroll
        for (int d = 0; d < 64; ++d) op[(size_t)d * (NH*N_)] = f2bf(acc[d]);
    }
}

// ---------------------------------------------------------------------------
// Convert projection weights f32 -> bf16 (512x512).
// ---------------------------------------------------------------------------
__global__ __launch_bounds__(256) void wconv_kernel(
    const float* __restrict__ w, bf16* __restrict__ wb)
{
    int i = blockIdx.x * 256 + threadIdx.x;   // 262144 total
    wb[i] = f2bf(w[i]);
}

// ---------------------------------------------------------------------------
// MFMA projection, LDS-staged (m97 structure + T2 swizzle):
//   out[b0+b_l][co][n] = sum_c Wb[co][c]*A[b_l][n][c] + pb[co]
// Tile 128(co) x 128(n), BK=64, 4 waves each owning a 64x64 quadrant.
// LDS tiles [128 rows][64 k] bf16, XOR-swizzled: logical (row, colbyte) lives
// at byte row*128 + (colbyte ^ ((row&7)<<4)). global_load_lds writes linearly,
// so the GLOBAL source applies the inverse permutation (same involution).
// ---------------------------------------------------------------------------
__global__ __launch_bounds__(256) void proj_mfma_kernel(
    const bf16* __restrict__ A, const bf16* __restrict__ Wb,
    const float* __restrict__ bias, float* __restrict__ out, int b0)
{
    __shared__ bf16 Ws_s[128 * 64];
    __shared__ bf16 As_s[128 * 64];
    int bid = blockIdx.x;                 // HB * 4 * 25
    int b_l = bid / 100; int rem = bid % 100;
    int mt = rem / 25, nt = rem % 25;
    int m0 = mt * 128, n0 = nt * 128;
    int t = threadIdx.x;
    int w = t >> 6, l = t & 63;
    int r16 = l & 15, kg = l >> 4;        // frag row / k-group
    int wr = w >> 1, wc = w & 1;          // wave quadrant
    const bf16* Ab = A + (size_t)b_l * N_ * C_;
    int rsub = l >> 3;                    // row within the 8-row wave chunk
    int colp = ((l & 7) ^ rsub) * 8;      // pre-swizzled k-element offset

    f32x4 acc[4][4];
#pragma unroll
    for (int i = 0; i < 4; ++i)
#pragma unroll
        for (int j = 0; j < 4; ++j) acc[i][j] = (f32x4){0.f, 0.f, 0.f, 0.f};

    for (int k0 = 0; k0 < C_; k0 += 64) {
        // stage W tile: rows m0..m0+127, k cols k0..k0+63
#pragma unroll
        for (int i = 0; i < 4; ++i) {
            int row = i * 32 + w * 8 + rsub;
            load_lds16(Wb + (size_t)(m0 + row) * C_ + k0 + colp,
                       (char*)Ws_s + i * 4096 + t * 16);
        }
        // stage A tile: rows n0..n0+127 (clamped), k cols k0..k0+63
#pragma unroll
        for (int i = 0; i < 4; ++i) {
            int row = i * 32 + w * 8 + rsub;
            int nn = n0 + row; if (nn >= N_) nn = N_ - 1;
            load_lds16(Ab + (size_t)nn * C_ + k0 + colp,
                       (char*)As_s + i * 4096 + t * 16);
        }
        __syncthreads();
#pragma unroll
        for (int ks = 0; ks < 2; ++ks) {
            short8 af[4], bfv[4];
#pragma unroll
            for (int mi = 0; mi < 4; ++mi) {
                int row = wr * 64 + mi * 16 + r16;
                int off = row * 128 + ((ks * 64 + kg * 16) ^ ((row & 7) << 4));
                af[mi] = *(const short8*)((const char*)Ws_s + off);
            }
#pragma unroll
            for (int nj = 0; nj < 4; ++nj) {
                int row = wc * 64 + nj * 16 + r16;
                int off = row * 128 + ((ks * 64 + kg * 16) ^ ((row & 7) << 4));
                bfv[nj] = *(const short8*)((const char*)As_s + off);
            }
#pragma unroll
            for (int mi = 0; mi < 4; ++mi)
#pragma unroll
                for (int nj = 0; nj < 4; ++nj)
                    acc[mi][nj] = __builtin_amdgcn_mfma_f32_16x16x32_bf16(
                        af[mi], bfv[nj], acc[mi][nj], 0, 0, 0);
        }
        __syncthreads();
    }
    // D layout: col = lane&15 (n), row = kg*4 + reg (co within 16)
    float* ob = out + ((size_t)(b0 + b_l) * C_) * N_;
#pragma unroll
    for (int mi = 0; mi < 4; ++mi) {
        int cobase = m0 + wr * 64 + mi * 16 + kg * 4;
#pragma unroll
        for (int r = 0; r < 4; ++r) {
            int co = cobase + r;
            float bi = bias[co];
#pragma unroll
            for (int nj = 0; nj < 4; ++nj) {
                int n = n0 + wc * 64 + nj * 16 + r16;
                if (n < N_) ob[(size_t)co * N_ + n] = acc[mi][nj][r] + bi;
            }
        }
    }
}

extern "C" void kernel_launch(void* const* d_in, const int* in_sizes, int n_in,
                              void* d_out, int out_size, void* d_ws, size_t ws_size,
                              hipStream_t stream) {
    const float* x     = (const float*)d_in[0];
    const float* cw    = (const float*)d_in[1];
    const float* gamma = (const float*)d_in[2];
    const float* beta  = (const float*)d_in[3];
    const float* mean  = (const float*)d_in[4];
    const float* var   = (const float*)d_in[5];
    const float* pw    = (const float*)d_in[6];
    const float* pb    = (const float*)d_in[7];
    float* out = (float*)d_out;

    const size_t QK_B   = (size_t)HB * 2 * C_ * N_ * sizeof(bf16);  // 51,380,224
    const size_t V_B    = (size_t)HB * C_ * N_ * sizeof(bf16);      // 25,690,112
    const size_t PART_B = (size_t)SPLIT * HB * NH * 4096 * 4;       //  7,340,032
    const size_t P_B    = (size_t)HB * NH * 4096 * 4;               //  1,048,576
    const size_t W_B    = (size_t)C_ * C_ * sizeof(bf16);           //    524,288
    char* wsp = (char*)d_ws;
    bool fast = ws_size >= QK_B + V_B + PART_B + P_B + W_B;         // 86.0 MB

    bf16* Wbf = fast ? (bf16*)(wsp + QK_B + V_B + PART_B + P_B)
                     : (bf16*)(wsp + QK_B + PART_B + P_B);
    wconv_kernel<<<(C_ * C_) / 256, 256, 0, stream>>>(pw, Wbf);

    for (int g = 0; g < 2; ++g) {
        int b0 = g * HB;
        if (fast) {
            bf16*  qk   = (bf16*)wsp;
            bf16*  v    = (bf16*)(wsp + QK_B);
            float* part = (float*)(wsp + QK_B + V_B);
            float* P    = (float*)(wsp + QK_B + V_B + PART_B);
            bf16*  outA = qk;   // reuse q,k region after gram
            conv_bn_kernel<<<(HB * C_ * N_) / 256, 256, 0, stream>>>(
                x, cw, gamma, beta, mean, var, qk, v, b0, 3);
            gram_kernel<<<HB * NH * SPLIT, 256, 0, stream>>>(qk, part);
            softmax_kernel<<<HB * NH * 64, 64, 0, stream>>>(part, P);
            pv_kernel<<<HB * NH * PV_TILES, 256, 0, stream>>>(v, P, outA);
            proj_mfma_kernel<<<HB * 4 * 25, 256, 0, stream>>>(outA, Wbf, pb, out, b0);
        } else {
            bf16*  qk   = (bf16*)wsp;
            float* part = (float*)(wsp + QK_B);
            float* P    = (float*)(wsp + QK_B + PART_B);
            bf16*  v    = qk;                       // reuse after gram
            bf16*  outA = (bf16*)(wsp + V_B);       // second half of qk region
            conv_bn_kernel<<<(HB * C_ * N_) / 256, 256, 0, stream>>>(
                x, cw, gamma, beta, mean, var, qk, (bf16*)nullptr, b0, 1);
            gram_kernel<<<HB * NH * SPLIT, 256, 0, stream>>>(qk, part);
            softmax_kernel<<<HB * NH * 64, 64, 0, stream>>>(part, P);
            conv_bn_kernel<<<(HB * C_ * N_) / 256, 256, 0, stream>>>(
                x, cw, gamma, beta, mean, var, (bf16*)nullptr, v, b0, 2);
            pv_kernel<<<HB * NH * PV_TILES, 256, 0, stream>>>(v, P, outA);
            proj_mfma_kernel<<<HB * 4 * 25, 256, 0, stream>>>(outA, Wbf, pb, out, b0);
        }
    }
}

// Round 6
// 438.600 us; speedup vs baseline: 1.8248x; 1.1686x over previous
//
#include <hip/hip_runtime.h>
#include <math.h>

#define B_ 16
#define HB 8             // batches per group (2 groups)
#define C_ 512
#define H_ 56
#define W_ 56
#define N_ 3136          // H_*W_
#define NH 8
#define HD 64
#define SPLIT 7          // n-split for gram; 3136/7 = 448
#define PV_TILES 13      // ceil(3136/256)
#define NG 784           // N_/4 pixel groups

typedef unsigned short bf16;
typedef __attribute__((ext_vector_type(8))) short short8;
typedef __attribute__((ext_vector_type(4))) float f32x4;

__device__ inline float bf2f(unsigned short u) {
    union { unsigned int i; float f; } v; v.i = ((unsigned int)u) << 16; return v.f;
}
__device__ inline unsigned short f2bf(float f) {
    union { float f; unsigned int i; } v; v.f = f;
    unsigned int r = v.i + 0x7fffu + ((v.i >> 16) & 1u);
    return (unsigned short)(r >> 16);
}

// async global->LDS, 16B per lane, linear dest (wave-uniform base + lane*16)
__device__ inline void load_lds16(const bf16* g, void* l) {
    __builtin_amdgcn_global_load_lds(
        (const __attribute__((address_space(1))) void*)g,
        (__attribute__((address_space(3))) void*)l, 16, 0, 0);
}

// ---------------------------------------------------------------------------
// Depthwise 3x3 conv + BN, 4-wide along n (4 | W so groups never straddle
// rows). wmask bit0: write q,k -> qkdst[(b_l*2+s)*C+c][n]. bit1: v -> vdst.
// ---------------------------------------------------------------------------
__global__ __launch_bounds__(256) void conv_bn_kernel(
    const float* __restrict__ x, const float* __restrict__ cw,
    const float* __restrict__ gamma, const float* __restrict__ beta,
    const float* __restrict__ mean, const float* __restrict__ var,
    bf16* __restrict__ qkdst, bf16* __restrict__ vdst, int b0, int wmask)
{
    int idx = blockIdx.x * 256 + threadIdx.x;   // over HB*C_*NG
    int g = idx % NG; int tmp = idx / NG;
    int ic = tmp % C_; int b_l = tmp / C_;
    int b = b0 + b_l;
    int n0 = g * 4;
    int yy = n0 / W_, xx0 = n0 % W_;            // xx0 in {0,4,...,52}
    const float* xin = x + ((size_t)b * C_ + ic) * N_;

    float vin[3][6];
#pragma unroll
    for (int dy = 0; dy < 3; ++dy) {
        int y2 = yy + dy - 1;
        bool rowok = (y2 >= 0) && (y2 < H_);
        const float* rp = xin + y2 * W_ + xx0;
        if (rowok) {
            float4 m = *(const float4*)rp;
            vin[dy][1] = m.x; vin[dy][2] = m.y; vin[dy][3] = m.z; vin[dy][4] = m.w;
            vin[dy][0] = (xx0 > 0)  ? rp[-1] : 0.f;
            vin[dy][5] = (xx0 < 52) ? rp[4]  : 0.f;
        } else {
#pragma unroll
            for (int j = 0; j < 6; ++j) vin[dy][j] = 0.f;
        }
    }
#pragma unroll
    for (int t = 0; t < 3; ++t) {
        int o = ic * 3 + t;                  // output channel in [0, 3C)
        int s = o >> 9;                      // 0=q 1=k 2=v
        int c = o & 511;
        bool doqk = (s < 2) && (wmask & 1);
        bool dov  = (s == 2) && (wmask & 2);
        if (doqk || dov) {
            const float* wp = cw + o * 9;
            float w9[9];
#pragma unroll
            for (int k = 0; k < 9; ++k) w9[k] = wp[k];
            float inv = gamma[o] * rsqrtf(var[o] + 1e-5f);
            float bias = fmaf(-mean[o], inv, beta[o]);
            ushort4 r4;
            unsigned short* rr = (unsigned short*)&r4;
#pragma unroll
            for (int j = 0; j < 4; ++j) {
                float acc = 0.f;
#pragma unroll
                for (int ky = 0; ky < 3; ++ky)
#pragma unroll
                    for (int kx = 0; kx < 3; ++kx)
                        acc = fmaf(vin[ky][j + kx], w9[ky*3+kx], acc);
                rr[j] = f2bf(fmaf(acc, inv, bias));
            }
            size_t off = doqk
                ? (((size_t)b_l * 2 + s) * C_ + c) * N_ + n0
                : ((size_t)b_l * C_ + c) * N_ + n0;
            bf16* dst = doqk ? qkdst : vdst;
            *(ushort4*)(dst + off) = r4;
        }
    }
}

// ---------------------------------------------------------------------------
// Gram partials: part[s][b_l*NH+h][d*64+e] = sum_{n in split s} q[d,n]*k[e,n]
// ---------------------------------------------------------------------------
__global__ __launch_bounds__(256) void gram_kernel(
    const bf16* __restrict__ qk, float* __restrict__ part)
{
    int bid = blockIdx.x;                 // HB*NH*SPLIT
    int s = bid % SPLIT; int bh = bid / SPLIT;
    int h = bh % NH; int b_l = bh / NH;
    const bf16* qp = qk + (((size_t)b_l * 2 + 0) * C_ + h * HD) * N_;
    const bf16* kp = qk + (((size_t)b_l * 2 + 1) * C_ + h * HD) * N_;
    int n0 = s * (N_ / SPLIT);            // 448 per split

    __shared__ float qs[64][68];
    __shared__ float ks[64][68];
    int t = threadIdx.x;
    int d0 = (t >> 4) << 2;
    int e0 = (t & 15) << 2;
    float acc[4][4] = {};

    for (int nc = 0; nc < N_ / SPLIT; nc += 64) {
        __syncthreads();
#pragma unroll
        for (int r = 0; r < 4; ++r) {
            int slot = r * 256 + t;       // 0..1023
            int row = slot >> 4, c4 = (slot & 15) << 2;
            ushort4 uq = *(const ushort4*)(qp + (size_t)row * N_ + n0 + nc + c4);
            ushort4 uk = *(const ushort4*)(kp + (size_t)row * N_ + n0 + nc + c4);
            qs[row][c4+0] = bf2f(uq.x); qs[row][c4+1] = bf2f(uq.y);
            qs[row][c4+2] = bf2f(uq.z); qs[row][c4+3] = bf2f(uq.w);
            ks[row][c4+0] = bf2f(uk.x); ks[row][c4+1] = bf2f(uk.y);
            ks[row][c4+2] = bf2f(uk.z); ks[row][c4+3] = bf2f(uk.w);
        }
        __syncthreads();
#pragma unroll
        for (int nn = 0; nn < 64; nn += 4) {
            float4 qa[4], ka[4];
#pragma unroll
            for (int i = 0; i < 4; ++i) qa[i] = *(const float4*)&qs[d0+i][nn];
#pragma unroll
            for (int j = 0; j < 4; ++j) ka[j] = *(const float4*)&ks[e0+j][nn];
#pragma unroll
            for (int i = 0; i < 4; ++i)
#pragma unroll
                for (int j = 0; j < 4; ++j)
                    acc[i][j] += qa[i].x*ka[j].x + qa[i].y*ka[j].y
                               + qa[i].z*ka[j].z + qa[i].w*ka[j].w;
        }
    }
    float* pp = part + ((size_t)s * (HB*NH) + bh) * 4096;
#pragma unroll
    for (int i = 0; i < 4; ++i)
#pragma unroll
        for (int j = 0; j < 4; ++j)
            pp[(d0+i) * 64 + (e0+j)] = acc[i][j];
}

// ---------------------------------------------------------------------------
// Reduce partials, scale, softmax over e. One wave per (bh,d) row.
// ---------------------------------------------------------------------------
__global__ __launch_bounds__(64) void softmax_kernel(
    const float* __restrict__ part, float* __restrict__ P)
{
    int row = blockIdx.x;                 // bh*64 + d
    int e = threadIdx.x;
    size_t base = (size_t)row * 64 + e;
    float val = 0.f;
#pragma unroll
    for (int s = 0; s < SPLIT; ++s) val += part[(size_t)s * (HB*NH*4096) + base];
    val *= 0.125f;                        // hd^-0.5
    float m = val;
#pragma unroll
    for (int off = 32; off > 0; off >>= 1) m = fmaxf(m, __shfl_xor(m, off));
    float ex = expf(val - m);
    float sum = ex;
#pragma unroll
    for (int off = 32; off > 0; off >>= 1) sum += __shfl_xor(sum, off);
    P[base] = ex / sum;
}

// ---------------------------------------------------------------------------
// outA[b_l][d][h][n] = sum_e P[b_l,h,d,e] * v[b_l][h*64+e][n]   (bf16 out)
// Flat [d][h][n] order == reference's swapaxes(1,2).reshape(B,N,C) layout.
// ---------------------------------------------------------------------------
__global__ __launch_bounds__(256) void pv_kernel(
    const bf16* __restrict__ v, const float* __restrict__ P,
    bf16* __restrict__ outA)
{
    int bid = blockIdx.x;
    int tile = bid % PV_TILES; int bh = bid / PV_TILES;
    int h = bh % NH, b_l = bh / NH;
    __shared__ float Pt[64][68];          // Pt[e][d]
    int t = threadIdx.x;
#pragma unroll
    for (int r = 0; r < 16; ++r) {
        int j = r * 256 + t; int d = j >> 6, e = j & 63;
        Pt[e][d] = P[(size_t)bh * 4096 + j];
    }
    __syncthreads();
    int n = tile * 256 + t;
    if (n < N_) {
        const bf16* vp = v + ((size_t)b_l * C_ + h * HD) * N_ + n;
        float acc[64];
#pragma unroll
        for (int d = 0; d < 64; ++d) acc[d] = 0.f;
        for (int e = 0; e < 64; ++e) {
            float ve = bf2f(vp[(size_t)e * N_]);
            const float4* pr = (const float4*)&Pt[e][0];
#pragma unroll
            for (int d4 = 0; d4 < 16; ++d4) {
                float4 p = pr[d4];
                acc[d4*4+0] = fmaf(p.x, ve, acc[d4*4+0]);
                acc[d4*4+1] = fmaf(p.y, ve, acc[d4*4+1]);
                acc[d4*4+2] = fmaf(p.z, ve, acc[d4*4+2]);
                acc[d4*4+3] = fmaf(p.w, ve, acc[d4*4+3]);
            }
        }
        bf16* op = outA + (size_t)b_l * (C_*N_) + (size_t)h * N_ + n;
#pragma unroll
        for (int d = 0; d < 64; ++d) op[(size_t)d * (NH*N_)] = f2bf(acc[d]);
    }
}

// ---------------------------------------------------------------------------
// Convert projection weights f32 -> bf16 (512x512).
// ---------------------------------------------------------------------------
__global__ __launch_bounds__(256) void wconv_kernel(
    const float* __restrict__ w, bf16* __restrict__ wb)
{
    int i = blockIdx.x * 256 + threadIdx.x;   // 262144 total
    wb[i] = f2bf(w[i]);
}

// ---------------------------------------------------------------------------
// MFMA projection, LDS-staged (m97 structure + T2 swizzle):
//   out[b0+b_l][co][n] = sum_c Wb[co][c]*A[b_l][n][c] + pb[co]
// Tile 128(co) x 128(n), BK=64, 4 waves each owning a 64x64 quadrant.
// ---------------------------------------------------------------------------
__global__ __launch_bounds__(256) void proj_mfma_kernel(
    const bf16* __restrict__ A, const bf16* __restrict__ Wb,
    const float* __restrict__ bias, float* __restrict__ out, int b0)
{
    __shared__ bf16 Ws_s[128 * 64];
    __shared__ bf16 As_s[128 * 64];
    int bid = blockIdx.x;                 // HB * 4 * 25
    int b_l = bid / 100; int rem = bid % 100;
    int mt = rem / 25, nt = rem % 25;
    int m0 = mt * 128, n0 = nt * 128;
    int t = threadIdx.x;
    int w = t >> 6, l = t & 63;
    int r16 = l & 15, kg = l >> 4;        // frag row / k-group
    int wr = w >> 1, wc = w & 1;          // wave quadrant
    const bf16* Ab = A + (size_t)b_l * N_ * C_;
    int rsub = l >> 3;                    // row within the 8-row wave chunk
    int colp = ((l & 7) ^ rsub) * 8;      // pre-swizzled k-element offset

    f32x4 acc[4][4];
#pragma unroll
    for (int i = 0; i < 4; ++i)
#pragma unroll
        for (int j = 0; j < 4; ++j) acc[i][j] = (f32x4){0.f, 0.f, 0.f, 0.f};

    for (int k0 = 0; k0 < C_; k0 += 64) {
#pragma unroll
        for (int i = 0; i < 4; ++i) {
            int row = i * 32 + w * 8 + rsub;
            load_lds16(Wb + (size_t)(m0 + row) * C_ + k0 + colp,
                       (char*)Ws_s + i * 4096 + t * 16);
        }
#pragma unroll
        for (int i = 0; i < 4; ++i) {
            int row = i * 32 + w * 8 + rsub;
            int nn = n0 + row; if (nn >= N_) nn = N_ - 1;
            load_lds16(Ab + (size_t)nn * C_ + k0 + colp,
                       (char*)As_s + i * 4096 + t * 16);
        }
        __syncthreads();
#pragma unroll
        for (int ks = 0; ks < 2; ++ks) {
            short8 af[4], bfv[4];
#pragma unroll
            for (int mi = 0; mi < 4; ++mi) {
                int row = wr * 64 + mi * 16 + r16;
                int off = row * 128 + ((ks * 64 + kg * 16) ^ ((row & 7) << 4));
                af[mi] = *(const short8*)((const char*)Ws_s + off);
            }
#pragma unroll
            for (int nj = 0; nj < 4; ++nj) {
                int row = wc * 64 + nj * 16 + r16;
                int off = row * 128 + ((ks * 64 + kg * 16) ^ ((row & 7) << 4));
                bfv[nj] = *(const short8*)((const char*)As_s + off);
            }
#pragma unroll
            for (int mi = 0; mi < 4; ++mi)
#pragma unroll
                for (int nj = 0; nj < 4; ++nj)
                    acc[mi][nj] = __builtin_amdgcn_mfma_f32_16x16x32_bf16(
                        af[mi], bfv[nj], acc[mi][nj], 0, 0, 0);
        }
        __syncthreads();
    }
    float* ob = out + ((size_t)(b0 + b_l) * C_) * N_;
#pragma unroll
    for (int mi = 0; mi < 4; ++mi) {
        int cobase = m0 + wr * 64 + mi * 16 + kg * 4;
#pragma unroll
        for (int r = 0; r < 4; ++r) {
            int co = cobase + r;
            float bi = bias[co];
#pragma unroll
            for (int nj = 0; nj < 4; ++nj) {
                int n = n0 + wc * 64 + nj * 16 + r16;
                if (n < N_) ob[(size_t)co * N_ + n] = acc[mi][nj][r] + bi;
            }
        }
    }
}

extern "C" void kernel_launch(void* const* d_in, const int* in_sizes, int n_in,
                              void* d_out, int out_size, void* d_ws, size_t ws_size,
                              hipStream_t stream) {
    const float* x     = (const float*)d_in[0];
    const float* cw    = (const float*)d_in[1];
    const float* gamma = (const float*)d_in[2];
    const float* beta  = (const float*)d_in[3];
    const float* mean  = (const float*)d_in[4];
    const float* var   = (const float*)d_in[5];
    const float* pw    = (const float*)d_in[6];
    const float* pb    = (const float*)d_in[7];
    float* out = (float*)d_out;

    const size_t QK_B   = (size_t)HB * 2 * C_ * N_ * sizeof(bf16);  // 51,380,224
    const size_t V_B    = (size_t)HB * C_ * N_ * sizeof(bf16);      // 25,690,112
    const size_t PART_B = (size_t)SPLIT * HB * NH * 4096 * 4;       //  7,340,032
    const size_t P_B    = (size_t)HB * NH * 4096 * 4;               //  1,048,576
    const size_t W_B    = (size_t)C_ * C_ * sizeof(bf16);           //    524,288
    char* wsp = (char*)d_ws;
    bool fast = ws_size >= QK_B + V_B + PART_B + P_B + W_B;         // 86.0 MB

    bf16* Wbf = fast ? (bf16*)(wsp + QK_B + V_B + PART_B + P_B)
                     : (bf16*)(wsp + QK_B + PART_B + P_B);
    wconv_kernel<<<(C_ * C_) / 256, 256, 0, stream>>>(pw, Wbf);

    for (int g = 0; g < 2; ++g) {
        int b0 = g * HB;
        if (fast) {
            bf16*  qk   = (bf16*)wsp;
            bf16*  v    = (bf16*)(wsp + QK_B);
            float* part = (float*)(wsp + QK_B + V_B);
            float* P    = (float*)(wsp + QK_B + V_B + PART_B);
            bf16*  outA = qk;   // reuse q,k region after gram
            conv_bn_kernel<<<(HB * C_ * NG) / 256, 256, 0, stream>>>(
                x, cw, gamma, beta, mean, var, qk, v, b0, 3);
            gram_kernel<<<HB * NH * SPLIT, 256, 0, stream>>>(qk, part);
            softmax_kernel<<<HB * NH * 64, 64, 0, stream>>>(part, P);
            pv_kernel<<<HB * NH * PV_TILES, 256, 0, stream>>>(v, P, outA);
            proj_mfma_kernel<<<HB * 4 * 25, 256, 0, stream>>>(outA, Wbf, pb, out, b0);
        } else {
            bf16*  qk   = (bf16*)wsp;
            float* part = (float*)(wsp + QK_B);
            float* P    = (float*)(wsp + QK_B + PART_B);
            bf16*  v    = qk;                       // reuse after gram
            bf16*  outA = (bf16*)(wsp + V_B);       // second half of qk region
            conv_bn_kernel<<<(HB * C_ * NG) / 256, 256, 0, stream>>>(
                x, cw, gamma, beta, mean, var, qk, (bf16*)nullptr, b0, 1);
            gram_kernel<<<HB * NH * SPLIT, 256, 0, stream>>>(qk, part);
            softmax_kernel<<<HB * NH * 64, 64, 0, stream>>>(part, P);
            conv_bn_kernel<<<(HB * C_ * NG) / 256, 256, 0, stream>>>(
                x, cw, gamma, beta, mean, var, (bf16*)nullptr, v, b0, 2);
            pv_kernel<<<HB * NH * PV_TILES, 256, 0, stream>>>(v, P, outA);
            proj_mfma_kernel<<<HB * 4 * 25, 256, 0, stream>>>(outA, Wbf, pb, out, b0);
        }
    }
}

// Round 7
// 274.367 us; speedup vs baseline: 2.9172x; 1.5986x over previous
//
#include <hip/hip_runtime.h>
#include <math.h>

#define B_ 16
#define HB 8             // batches per group (2 groups)
#define C_ 512
#define H_ 56
#define W_ 56
#define N_ 3136          // H_*W_ = 49*64
#define NH 8
#define HD 64
#define SPLIT 7          // n-split for gram; 3136/7 = 448
#define NG 784           // N_/4 pixel groups

typedef unsigned short bf16;
typedef __attribute__((ext_vector_type(8))) short short8;
typedef __attribute__((ext_vector_type(4))) float f32x4;

__device__ inline float bf2f(unsigned short u) {
    union { unsigned int i; float f; } v; v.i = ((unsigned int)u) << 16; return v.f;
}
__device__ inline unsigned short f2bf(float f) {
    union { float f; unsigned int i; } v; v.f = f;
    unsigned int r = v.i + 0x7fffu + ((v.i >> 16) & 1u);
    return (unsigned short)(r >> 16);
}

// async global->LDS, 16B per lane, linear dest (wave-uniform base + lane*16)
__device__ inline void load_lds16(const void* g, void* l) {
    __builtin_amdgcn_global_load_lds(
        (const __attribute__((address_space(1))) void*)g,
        (__attribute__((address_space(3))) void*)l, 16, 0, 0);
}

// ---------------------------------------------------------------------------
// Depthwise 3x3 conv + BN, 4-wide along n (4 | W so groups never straddle
// rows). wmask bit0: write q,k -> qkdst[(b_l*2+s)*C+c][n]. bit1: v -> vdst.
// ---------------------------------------------------------------------------
__global__ __launch_bounds__(256) void conv_bn_kernel(
    const float* __restrict__ x, const float* __restrict__ cw,
    const float* __restrict__ gamma, const float* __restrict__ beta,
    const float* __restrict__ mean, const float* __restrict__ var,
    bf16* __restrict__ qkdst, bf16* __restrict__ vdst, int b0, int wmask)
{
    int idx = blockIdx.x * 256 + threadIdx.x;   // over HB*C_*NG
    int g = idx % NG; int tmp = idx / NG;
    int ic = tmp % C_; int b_l = tmp / C_;
    int b = b0 + b_l;
    int n0 = g * 4;
    int yy = n0 / W_, xx0 = n0 % W_;            // xx0 in {0,4,...,52}
    const float* xin = x + ((size_t)b * C_ + ic) * N_;

    float vin[3][6];
#pragma unroll
    for (int dy = 0; dy < 3; ++dy) {
        int y2 = yy + dy - 1;
        bool rowok = (y2 >= 0) && (y2 < H_);
        const float* rp = xin + y2 * W_ + xx0;
        if (rowok) {
            float4 m = *(const float4*)rp;
            vin[dy][1] = m.x; vin[dy][2] = m.y; vin[dy][3] = m.z; vin[dy][4] = m.w;
            vin[dy][0] = (xx0 > 0)  ? rp[-1] : 0.f;
            vin[dy][5] = (xx0 < 52) ? rp[4]  : 0.f;
        } else {
#pragma unroll
            for (int j = 0; j < 6; ++j) vin[dy][j] = 0.f;
        }
    }
#pragma unroll
    for (int t = 0; t < 3; ++t) {
        int o = ic * 3 + t;                  // output channel in [0, 3C)
        int s = o >> 9;                      // 0=q 1=k 2=v
        int c = o & 511;
        bool doqk = (s < 2) && (wmask & 1);
        bool dov  = (s == 2) && (wmask & 2);
        if (doqk || dov) {
            const float* wp = cw + o * 9;
            float w9[9];
#pragma unroll
            for (int k = 0; k < 9; ++k) w9[k] = wp[k];
            float inv = gamma[o] * rsqrtf(var[o] + 1e-5f);
            float bias = fmaf(-mean[o], inv, beta[o]);
            ushort4 r4;
            unsigned short* rr = (unsigned short*)&r4;
#pragma unroll
            for (int j = 0; j < 4; ++j) {
                float acc = 0.f;
#pragma unroll
                for (int ky = 0; ky < 3; ++ky)
#pragma unroll
                    for (int kx = 0; kx < 3; ++kx)
                        acc = fmaf(vin[ky][j + kx], w9[ky*3+kx], acc);
                rr[j] = f2bf(fmaf(acc, inv, bias));
            }
            size_t off = doqk
                ? (((size_t)b_l * 2 + s) * C_ + c) * N_ + n0
                : ((size_t)b_l * C_ + c) * N_ + n0;
            bf16* dst = doqk ? qkdst : vdst;
            *(ushort4*)(dst + off) = r4;
        }
    }
}

// ---------------------------------------------------------------------------
// Gram partials via MFMA (same structure as proj: T2 swizzle + gload_lds):
//   part[s][bh][d*64+e] = sum_{n in split s} q[d,n]*k[e,n]
// Block = (b_l,h,s), 4 waves; wave (wr,wc) owns a 32x32 quadrant (2x2 frags).
// LDS tiles [64 rows][64 n] bf16, XOR-swizzled via pre-swizzled global src.
// ---------------------------------------------------------------------------
__global__ __launch_bounds__(256) void gram_mfma_kernel(
    const bf16* __restrict__ qk, float* __restrict__ part)
{
    __shared__ bf16 qs[64 * 64];
    __shared__ bf16 ks[64 * 64];
    int bid = blockIdx.x;                 // HB*NH*SPLIT
    int s = bid % SPLIT; int bh = bid / SPLIT;
    int h = bh % NH; int b_l = bh / NH;
    const bf16* qp = qk + (((size_t)b_l * 2 + 0) * C_ + h * HD) * N_;
    const bf16* kp = qk + (((size_t)b_l * 2 + 1) * C_ + h * HD) * N_;
    int t = threadIdx.x;
    int w = t >> 6, l = t & 63;
    int r16 = l & 15, kg = l >> 4;
    int wr = w >> 1, wc = w & 1;
    int rsub = l >> 3;
    int colp = ((l & 7) ^ rsub) * 8;      // pre-swizzled n-element offset
    int n0 = s * (N_ / SPLIT);

    f32x4 acc[2][2];
#pragma unroll
    for (int i = 0; i < 2; ++i)
#pragma unroll
        for (int j = 0; j < 2; ++j) acc[i][j] = (f32x4){0.f, 0.f, 0.f, 0.f};

    for (int nc = 0; nc < N_ / SPLIT; nc += 64) {
        int nb = n0 + nc;
#pragma unroll
        for (int i = 0; i < 2; ++i) {
            int row = i * 32 + w * 8 + rsub;
            load_lds16(qp + (size_t)row * N_ + nb + colp, (char*)qs + i * 4096 + t * 16);
            load_lds16(kp + (size_t)row * N_ + nb + colp, (char*)ks + i * 4096 + t * 16);
        }
        __syncthreads();
#pragma unroll
        for (int ksb = 0; ksb < 2; ++ksb) {
            short8 af[2], bfv[2];
#pragma unroll
            for (int mi = 0; mi < 2; ++mi) {
                int row = wr * 32 + mi * 16 + r16;
                int off = row * 128 + ((ksb * 64 + kg * 16) ^ ((row & 7) << 4));
                af[mi] = *(const short8*)((const char*)qs + off);
            }
#pragma unroll
            for (int nj = 0; nj < 2; ++nj) {
                int row = wc * 32 + nj * 16 + r16;
                int off = row * 128 + ((ksb * 64 + kg * 16) ^ ((row & 7) << 4));
                bfv[nj] = *(const short8*)((const char*)ks + off);
            }
#pragma unroll
            for (int mi = 0; mi < 2; ++mi)
#pragma unroll
                for (int nj = 0; nj < 2; ++nj)
                    acc[mi][nj] = __builtin_amdgcn_mfma_f32_16x16x32_bf16(
                        af[mi], bfv[nj], acc[mi][nj], 0, 0, 0);
        }
        __syncthreads();
    }
    // D layout: col(e) = lane&15, row(d within 16) = kg*4 + reg
    float* pp = part + ((size_t)s * (HB*NH) + bh) * 4096;
#pragma unroll
    for (int mi = 0; mi < 2; ++mi)
#pragma unroll
        for (int nj = 0; nj < 2; ++nj) {
            int e = wc * 32 + nj * 16 + r16;
#pragma unroll
            for (int r = 0; r < 4; ++r) {
                int d = wr * 32 + mi * 16 + kg * 4 + r;
                pp[d * 64 + e] = acc[mi][nj][r];
            }
        }
}

// ---------------------------------------------------------------------------
// Reduce partials, scale, softmax over e. One wave per (bh,d) row.
// Writes P TRANSPOSED: PT[bh][e*64+d] so pv can stage it linearly.
// ---------------------------------------------------------------------------
__global__ __launch_bounds__(64) void softmax_kernel(
    const float* __restrict__ part, float* __restrict__ PT)
{
    int row = blockIdx.x;                 // bh*64 + d
    int e = threadIdx.x;
    size_t base = (size_t)row * 64 + e;
    float val = 0.f;
#pragma unroll
    for (int s = 0; s < SPLIT; ++s) val += part[(size_t)s * (HB*NH*4096) + base];
    val *= 0.125f;                        // hd^-0.5
    float m = val;
#pragma unroll
    for (int off = 32; off > 0; off >>= 1) m = fmaxf(m, __shfl_xor(m, off));
    float ex = expf(val - m);
    float sum = ex;
#pragma unroll
    for (int off = 32; off > 0; off >>= 1) sum += __shfl_xor(sum, off);
    PT[(size_t)(row >> 6) * 4096 + (size_t)e * 64 + (row & 63)] = ex / sum;
}

// ---------------------------------------------------------------------------
// outA[b_l][d][h][n] = sum_e PT[e][d] * v[b_l][h*64+e][n]   (bf16 out)
// Block = (bh, 64-n tile): stages PT (16KB f32) + v tile (8KB bf16) via
// gload_lds, then thread (ng,dg) computes a 4n x 4d patch. N_=49*64 exact.
// ---------------------------------------------------------------------------
__global__ __launch_bounds__(256) void pv_kernel(
    const bf16* __restrict__ v, const float* __restrict__ PT,
    bf16* __restrict__ outA)
{
    __shared__ float pts[4096];           // PT[e][d] 16KB
    __shared__ bf16 vs[64 * 64];          // vs[e][n] 8KB
    int bid = blockIdx.x;                 // HB*NH*49
    int nt = bid % 49; int bh = bid / 49;
    int h = bh % NH, b_l = bh / NH;
    int t = threadIdx.x;
    const float* ptg = PT + (size_t)bh * 4096;
#pragma unroll
    for (int i = 0; i < 4; ++i)
        load_lds16(ptg + i * 1024 + t * 4, (char*)pts + i * 4096 + t * 16);
    const bf16* vb = v + ((size_t)b_l * C_ + h * HD) * N_ + nt * 64;
#pragma unroll
    for (int i = 0; i < 2; ++i) {
        int row = i * 32 + (t >> 3);
        load_lds16(vb + (size_t)row * N_ + (t & 7) * 8, (char*)vs + i * 4096 + t * 16);
    }
    __syncthreads();

    int ng = t & 15, dg = t >> 4;         // n0 = ng*4, d0 = dg*4
    float acc[4][4] = {};
#pragma unroll 16
    for (int e = 0; e < 64; ++e) {
        float4 p = *(const float4*)&pts[e * 64 + dg * 4];
        ushort4 vv = *(const ushort4*)&vs[e * 64 + ng * 4];
        float v0 = bf2f(vv.x), v1 = bf2f(vv.y), v2 = bf2f(vv.z), v3 = bf2f(vv.w);
        float p4[4] = {p.x, p.y, p.z, p.w};
#pragma unroll
        for (int i = 0; i < 4; ++i) {
            acc[i][0] = fmaf(p4[i], v0, acc[i][0]);
            acc[i][1] = fmaf(p4[i], v1, acc[i][1]);
            acc[i][2] = fmaf(p4[i], v2, acc[i][2]);
            acc[i][3] = fmaf(p4[i], v3, acc[i][3]);
        }
    }
    bf16* op = outA + (size_t)b_l * (C_*N_) + (size_t)h * N_ + nt * 64 + ng * 4;
#pragma unroll
    for (int i = 0; i < 4; ++i) {
        ushort4 r4;
        unsigned short* rr = (unsigned short*)&r4;
        rr[0] = f2bf(acc[i][0]); rr[1] = f2bf(acc[i][1]);
        rr[2] = f2bf(acc[i][2]); rr[3] = f2bf(acc[i][3]);
        *(ushort4*)(op + (size_t)(dg * 4 + i) * (NH*N_)) = r4;
    }
}

// ---------------------------------------------------------------------------
// Convert projection weights f32 -> bf16 (512x512).
// ---------------------------------------------------------------------------
__global__ __launch_bounds__(256) void wconv_kernel(
    const float* __restrict__ w, bf16* __restrict__ wb)
{
    int i = blockIdx.x * 256 + threadIdx.x;   // 262144 total
    wb[i] = f2bf(w[i]);
}

// ---------------------------------------------------------------------------
// MFMA projection, LDS-staged (m97 structure + T2 swizzle):
//   out[b0+b_l][co][n] = sum_c Wb[co][c]*A[b_l][n][c] + pb[co]
// Tile 128(co) x 128(n), BK=64, 4 waves each owning a 64x64 quadrant.
// ---------------------------------------------------------------------------
__global__ __launch_bounds__(256) void proj_mfma_kernel(
    const bf16* __restrict__ A, const bf16* __restrict__ Wb,
    const float* __restrict__ bias, float* __restrict__ out, int b0)
{
    __shared__ bf16 Ws_s[128 * 64];
    __shared__ bf16 As_s[128 * 64];
    int bid = blockIdx.x;                 // HB * 4 * 25
    int b_l = bid / 100; int rem = bid % 100;
    int mt = rem / 25, nt = rem % 25;
    int m0 = mt * 128, n0 = nt * 128;
    int t = threadIdx.x;
    int w = t >> 6, l = t & 63;
    int r16 = l & 15, kg = l >> 4;        // frag row / k-group
    int wr = w >> 1, wc = w & 1;          // wave quadrant
    const bf16* Ab = A + (size_t)b_l * N_ * C_;
    int rsub = l >> 3;                    // row within the 8-row wave chunk
    int colp = ((l & 7) ^ rsub) * 8;      // pre-swizzled k-element offset

    f32x4 acc[4][4];
#pragma unroll
    for (int i = 0; i < 4; ++i)
#pragma unroll
        for (int j = 0; j < 4; ++j) acc[i][j] = (f32x4){0.f, 0.f, 0.f, 0.f};

    for (int k0 = 0; k0 < C_; k0 += 64) {
#pragma unroll
        for (int i = 0; i < 4; ++i) {
            int row = i * 32 + w * 8 + rsub;
            load_lds16(Wb + (size_t)(m0 + row) * C_ + k0 + colp,
                       (char*)Ws_s + i * 4096 + t * 16);
        }
#pragma unroll
        for (int i = 0; i < 4; ++i) {
            int row = i * 32 + w * 8 + rsub;
            int nn = n0 + row; if (nn >= N_) nn = N_ - 1;
            load_lds16(Ab + (size_t)nn * C_ + k0 + colp,
                       (char*)As_s + i * 4096 + t * 16);
        }
        __syncthreads();
#pragma unroll
        for (int ks = 0; ks < 2; ++ks) {
            short8 af[4], bfv[4];
#pragma unroll
            for (int mi = 0; mi < 4; ++mi) {
                int row = wr * 64 + mi * 16 + r16;
                int off = row * 128 + ((ks * 64 + kg * 16) ^ ((row & 7) << 4));
                af[mi] = *(const short8*)((const char*)Ws_s + off);
            }
#pragma unroll
            for (int nj = 0; nj < 4; ++nj) {
                int row = wc * 64 + nj * 16 + r16;
                int off = row * 128 + ((ks * 64 + kg * 16) ^ ((row & 7) << 4));
                bfv[nj] = *(const short8*)((const char*)As_s + off);
            }
#pragma unroll
            for (int mi = 0; mi < 4; ++mi)
#pragma unroll
                for (int nj = 0; nj < 4; ++nj)
                    acc[mi][nj] = __builtin_amdgcn_mfma_f32_16x16x32_bf16(
                        af[mi], bfv[nj], acc[mi][nj], 0, 0, 0);
        }
        __syncthreads();
    }
    float* ob = out + ((size_t)(b0 + b_l) * C_) * N_;
#pragma unroll
    for (int mi = 0; mi < 4; ++mi) {
        int cobase = m0 + wr * 64 + mi * 16 + kg * 4;
#pragma unroll
        for (int r = 0; r < 4; ++r) {
            int co = cobase + r;
            float bi = bias[co];
#pragma unroll
            for (int nj = 0; nj < 4; ++nj) {
                int n = n0 + wc * 64 + nj * 16 + r16;
                if (n < N_) ob[(size_t)co * N_ + n] = acc[mi][nj][r] + bi;
            }
        }
    }
}

extern "C" void kernel_launch(void* const* d_in, const int* in_sizes, int n_in,
                              void* d_out, int out_size, void* d_ws, size_t ws_size,
                              hipStream_t stream) {
    const float* x     = (const float*)d_in[0];
    const float* cw    = (const float*)d_in[1];
    const float* gamma = (const float*)d_in[2];
    const float* beta  = (const float*)d_in[3];
    const float* mean  = (const float*)d_in[4];
    const float* var   = (const float*)d_in[5];
    const float* pw    = (const float*)d_in[6];
    const float* pb    = (const float*)d_in[7];
    float* out = (float*)d_out;

    const size_t QK_B   = (size_t)HB * 2 * C_ * N_ * sizeof(bf16);  // 51,380,224
    const size_t V_B    = (size_t)HB * C_ * N_ * sizeof(bf16);      // 25,690,112
    const size_t PART_B = (size_t)SPLIT * HB * NH * 4096 * 4;       //  7,340,032
    const size_t P_B    = (size_t)HB * NH * 4096 * 4;               //  1,048,576
    const size_t W_B    = (size_t)C_ * C_ * sizeof(bf16);           //    524,288
    char* wsp = (char*)d_ws;
    bool fast = ws_size >= QK_B + V_B + PART_B + P_B + W_B;         // 86.0 MB

    bf16* Wbf = fast ? (bf16*)(wsp + QK_B + V_B + PART_B + P_B)
                     : (bf16*)(wsp + QK_B + PART_B + P_B);
    wconv_kernel<<<(C_ * C_) / 256, 256, 0, stream>>>(pw, Wbf);

    for (int g = 0; g < 2; ++g) {
        int b0 = g * HB;
        if (fast) {
            bf16*  qk   = (bf16*)wsp;
            bf16*  v    = (bf16*)(wsp + QK_B);
            float* part = (float*)(wsp + QK_B + V_B);
            float* PT   = (float*)(wsp + QK_B + V_B + PART_B);
            bf16*  outA = qk;   // reuse q,k region after gram
            conv_bn_kernel<<<(HB * C_ * NG) / 256, 256, 0, stream>>>(
                x, cw, gamma, beta, mean, var, qk, v, b0, 3);
            gram_mfma_kernel<<<HB * NH * SPLIT, 256, 0, stream>>>(qk, part);
            softmax_kernel<<<HB * NH * 64, 64, 0, stream>>>(part, PT);
            pv_kernel<<<HB * NH * 49, 256, 0, stream>>>(v, PT, outA);
            proj_mfma_kernel<<<HB * 4 * 25, 256, 0, stream>>>(outA, Wbf, pb, out, b0);
        } else {
            bf16*  qk   = (bf16*)wsp;
            float* part = (float*)(wsp + QK_B);
            float* PT   = (float*)(wsp + QK_B + PART_B);
            bf16*  v    = qk;                       // reuse after gram
            bf16*  outA = (bf16*)(wsp + V_B);       // second half of qk region
            conv_bn_kernel<<<(HB * C_ * NG) / 256, 256, 0, stream>>>(
                x, cw, gamma, beta, mean, var, qk, (bf16*)nullptr, b0, 1);
            gram_mfma_kernel<<<HB * NH * SPLIT, 256, 0, stream>>>(qk, part);
            softmax_kernel<<<HB * NH * 64, 64, 0, stream>>>(part, PT);
            conv_bn_kernel<<<(HB * C_ * NG) / 256, 256, 0, stream>>>(
                x, cw, gamma, beta, mean, var, (bf16*)nullptr, v, b0, 2);
            pv_kernel<<<HB * NH * 49, 256, 0, stream>>>(v, PT, outA);
            proj_mfma_kernel<<<HB * 4 * 25, 256, 0, stream>>>(outA, Wbf, pb, out, b0);
        }
    }
}

// Round 8
// 253.697 us; speedup vs baseline: 3.1548x; 1.0815x over previous
//
#include <hip/hip_runtime.h>
#include <math.h>

#define B_ 16
#define HB 8             // batches per group (2 groups)
#define C_ 512
#define H_ 56
#define W_ 56
#define N_ 3136          // H_*W_ = 49*64
#define NH 8
#define HD 64
#define SPLIT 7          // n-split for gram; 3136/7 = 448
#define NG 784           // N_/4 pixel groups

typedef unsigned short bf16;
typedef __attribute__((ext_vector_type(8))) short short8;
typedef __attribute__((ext_vector_type(4))) float f32x4;

__device__ inline float bf2f(unsigned short u) {
    union { unsigned int i; float f; } v; v.i = ((unsigned int)u) << 16; return v.f;
}
__device__ inline unsigned short f2bf(float f) {
    union { float f; unsigned int i; } v; v.f = f;
    unsigned int r = v.i + 0x7fffu + ((v.i >> 16) & 1u);
    return (unsigned short)(r >> 16);
}

// async global->LDS, 16B per lane, linear dest (wave-uniform base + lane*16)
__device__ inline void load_lds16(const void* g, void* l) {
    __builtin_amdgcn_global_load_lds(
        (const __attribute__((address_space(1))) void*)g,
        (__attribute__((address_space(3))) void*)l, 16, 0, 0);
}

// ---------------------------------------------------------------------------
// Depthwise 3x3 conv + BN. One block per (b_l, ic): filter taps + BN params
// are block-uniform (scalar loads, amortized over all 3136 pixels). 256
// threads grid-stride over 784 4-pixel groups (4 | W, no row straddle).
// wmask bit0: write q,k -> qkdst[(b_l*2+s)*C+c][n]. bit1: v -> vdst.
// ---------------------------------------------------------------------------
__global__ __launch_bounds__(256) void conv_bn_kernel(
    const float* __restrict__ x, const float* __restrict__ cw,
    const float* __restrict__ gamma, const float* __restrict__ beta,
    const float* __restrict__ mean, const float* __restrict__ var,
    bf16* __restrict__ qkdst, bf16* __restrict__ vdst, int b0, int wmask)
{
    int bid = blockIdx.x;                 // HB*C_
    int ic = bid & 511; int b_l = bid >> 9;
    int b = b0 + b_l;
    const float* xin = x + ((size_t)b * C_ + ic) * N_;

    // block-uniform filter + BN constants (scalar loads)
    float w9[3][9], inv3[3], bias3[3];
#pragma unroll
    for (int t = 0; t < 3; ++t) {
        int o = ic * 3 + t;
#pragma unroll
        for (int k = 0; k < 9; ++k) w9[t][k] = cw[o * 9 + k];
        float iv = gamma[o] * rsqrtf(var[o] + 1e-5f);
        inv3[t] = iv;
        bias3[t] = fmaf(-mean[o], iv, beta[o]);
    }

    for (int g = threadIdx.x; g < NG; g += 256) {
        int yy = g / 14;                  // n0 = g*4 = yy*56 + xx0
        int xx0 = (g - yy * 14) * 4;
        int n0 = g * 4;
        float vin[3][6];
#pragma unroll
        for (int dy = 0; dy < 3; ++dy) {
            int y2 = yy + dy - 1;
            bool rowok = (y2 >= 0) && (y2 < H_);
            const float* rp = xin + y2 * W_ + xx0;
            if (rowok) {
                float4 m = *(const float4*)rp;
                vin[dy][1] = m.x; vin[dy][2] = m.y; vin[dy][3] = m.z; vin[dy][4] = m.w;
                vin[dy][0] = (xx0 > 0)  ? rp[-1] : 0.f;
                vin[dy][5] = (xx0 < 52) ? rp[4]  : 0.f;
            } else {
#pragma unroll
                for (int j = 0; j < 6; ++j) vin[dy][j] = 0.f;
            }
        }
#pragma unroll
        for (int t = 0; t < 3; ++t) {
            int o = ic * 3 + t;           // uniform
            int s = o >> 9;               // uniform: 0=q 1=k 2=v
            int c = o & 511;
            bool doqk = (s < 2) && (wmask & 1);
            bool dov  = (s == 2) && (wmask & 2);
            if (doqk || dov) {
                ushort4 r4;
                unsigned short* rr = (unsigned short*)&r4;
#pragma unroll
                for (int j = 0; j < 4; ++j) {
                    float acc = 0.f;
#pragma unroll
                    for (int ky = 0; ky < 3; ++ky)
#pragma unroll
                        for (int kx = 0; kx < 3; ++kx)
                            acc = fmaf(vin[ky][j + kx], w9[t][ky*3+kx], acc);
                    rr[j] = f2bf(fmaf(acc, inv3[t], bias3[t]));
                }
                size_t off = doqk
                    ? (((size_t)b_l * 2 + s) * C_ + c) * N_ + n0
                    : ((size_t)b_l * C_ + c) * N_ + n0;
                bf16* dst = doqk ? qkdst : vdst;
                *(ushort4*)(dst + off) = r4;
            }
        }
    }
}

// ---------------------------------------------------------------------------
// Gram partials via MFMA (T2 swizzle + gload_lds):
//   part[s][bh][d*64+e] = sum_{n in split s} q[d,n]*k[e,n]
// ---------------------------------------------------------------------------
__global__ __launch_bounds__(256) void gram_mfma_kernel(
    const bf16* __restrict__ qk, float* __restrict__ part)
{
    __shared__ bf16 qs[64 * 64];
    __shared__ bf16 ks[64 * 64];
    int bid = blockIdx.x;                 // HB*NH*SPLIT
    int s = bid % SPLIT; int bh = bid / SPLIT;
    int h = bh % NH; int b_l = bh / NH;
    const bf16* qp = qk + (((size_t)b_l * 2 + 0) * C_ + h * HD) * N_;
    const bf16* kp = qk + (((size_t)b_l * 2 + 1) * C_ + h * HD) * N_;
    int t = threadIdx.x;
    int w = t >> 6, l = t & 63;
    int r16 = l & 15, kg = l >> 4;
    int wr = w >> 1, wc = w & 1;
    int rsub = l >> 3;
    int colp = ((l & 7) ^ rsub) * 8;      // pre-swizzled n-element offset
    int n0 = s * (N_ / SPLIT);

    f32x4 acc[2][2];
#pragma unroll
    for (int i = 0; i < 2; ++i)
#pragma unroll
        for (int j = 0; j < 2; ++j) acc[i][j] = (f32x4){0.f, 0.f, 0.f, 0.f};

    for (int nc = 0; nc < N_ / SPLIT; nc += 64) {
        int nb = n0 + nc;
#pragma unroll
        for (int i = 0; i < 2; ++i) {
            int row = i * 32 + w * 8 + rsub;
            load_lds16(qp + (size_t)row * N_ + nb + colp, (char*)qs + i * 4096 + t * 16);
            load_lds16(kp + (size_t)row * N_ + nb + colp, (char*)ks + i * 4096 + t * 16);
        }
        __syncthreads();
#pragma unroll
        for (int ksb = 0; ksb < 2; ++ksb) {
            short8 af[2], bfv[2];
#pragma unroll
            for (int mi = 0; mi < 2; ++mi) {
                int row = wr * 32 + mi * 16 + r16;
                int off = row * 128 + ((ksb * 64 + kg * 16) ^ ((row & 7) << 4));
                af[mi] = *(const short8*)((const char*)qs + off);
            }
#pragma unroll
            for (int nj = 0; nj < 2; ++nj) {
                int row = wc * 32 + nj * 16 + r16;
                int off = row * 128 + ((ksb * 64 + kg * 16) ^ ((row & 7) << 4));
                bfv[nj] = *(const short8*)((const char*)ks + off);
            }
#pragma unroll
            for (int mi = 0; mi < 2; ++mi)
#pragma unroll
                for (int nj = 0; nj < 2; ++nj)
                    acc[mi][nj] = __builtin_amdgcn_mfma_f32_16x16x32_bf16(
                        af[mi], bfv[nj], acc[mi][nj], 0, 0, 0);
        }
        __syncthreads();
    }
    float* pp = part + ((size_t)s * (HB*NH) + bh) * 4096;
#pragma unroll
    for (int mi = 0; mi < 2; ++mi)
#pragma unroll
        for (int nj = 0; nj < 2; ++nj) {
            int e = wc * 32 + nj * 16 + r16;
#pragma unroll
            for (int r = 0; r < 4; ++r) {
                int d = wr * 32 + mi * 16 + kg * 4 + r;
                pp[d * 64 + e] = acc[mi][nj][r];
            }
        }
}

// ---------------------------------------------------------------------------
// Reduce partials, scale, softmax over e. One wave per (bh,d) row.
// Writes P TRANSPOSED: PT[bh][e*64+d] so pv can stage it linearly.
// ---------------------------------------------------------------------------
__global__ __launch_bounds__(64) void softmax_kernel(
    const float* __restrict__ part, float* __restrict__ PT)
{
    int row = blockIdx.x;                 // bh*64 + d
    int e = threadIdx.x;
    size_t base = (size_t)row * 64 + e;
    float val = 0.f;
#pragma unroll
    for (int s = 0; s < SPLIT; ++s) val += part[(size_t)s * (HB*NH*4096) + base];
    val *= 0.125f;                        // hd^-0.5
    float m = val;
#pragma unroll
    for (int off = 32; off > 0; off >>= 1) m = fmaxf(m, __shfl_xor(m, off));
    float ex = expf(val - m);
    float sum = ex;
#pragma unroll
    for (int off = 32; off > 0; off >>= 1) sum += __shfl_xor(sum, off);
    PT[(size_t)(row >> 6) * 4096 + (size_t)e * 64 + (row & 63)] = ex / sum;
}

// ---------------------------------------------------------------------------
// outA[b_l][d][h][n] = sum_e PT[e][d] * v[b_l][h*64+e][n]   (bf16 out)
// ---------------------------------------------------------------------------
__global__ __launch_bounds__(256) void pv_kernel(
    const bf16* __restrict__ v, const float* __restrict__ PT,
    bf16* __restrict__ outA)
{
    __shared__ float pts[4096];           // PT[e][d] 16KB
    __shared__ bf16 vs[64 * 64];          // vs[e][n] 8KB
    int bid = blockIdx.x;                 // HB*NH*49
    int nt = bid % 49; int bh = bid / 49;
    int h = bh % NH, b_l = bh / NH;
    int t = threadIdx.x;
    const float* ptg = PT + (size_t)bh * 4096;
#pragma unroll
    for (int i = 0; i < 4; ++i)
        load_lds16(ptg + i * 1024 + t * 4, (char*)pts + i * 4096 + t * 16);
    const bf16* vb = v + ((size_t)b_l * C_ + h * HD) * N_ + nt * 64;
#pragma unroll
    for (int i = 0; i < 2; ++i) {
        int row = i * 32 + (t >> 3);
        load_lds16(vb + (size_t)row * N_ + (t & 7) * 8, (char*)vs + i * 4096 + t * 16);
    }
    __syncthreads();

    int ng = t & 15, dg = t >> 4;         // n0 = ng*4, d0 = dg*4
    float acc[4][4] = {};
#pragma unroll 16
    for (int e = 0; e < 64; ++e) {
        float4 p = *(const float4*)&pts[e * 64 + dg * 4];
        ushort4 vv = *(const ushort4*)&vs[e * 64 + ng * 4];
        float v0 = bf2f(vv.x), v1 = bf2f(vv.y), v2 = bf2f(vv.z), v3 = bf2f(vv.w);
        float p4[4] = {p.x, p.y, p.z, p.w};
#pragma unroll
        for (int i = 0; i < 4; ++i) {
            acc[i][0] = fmaf(p4[i], v0, acc[i][0]);
            acc[i][1] = fmaf(p4[i], v1, acc[i][1]);
            acc[i][2] = fmaf(p4[i], v2, acc[i][2]);
            acc[i][3] = fmaf(p4[i], v3, acc[i][3]);
        }
    }
    bf16* op = outA + (size_t)b_l * (C_*N_) + (size_t)h * N_ + nt * 64 + ng * 4;
#pragma unroll
    for (int i = 0; i < 4; ++i) {
        ushort4 r4;
        unsigned short* rr = (unsigned short*)&r4;
        rr[0] = f2bf(acc[i][0]); rr[1] = f2bf(acc[i][1]);
        rr[2] = f2bf(acc[i][2]); rr[3] = f2bf(acc[i][3]);
        *(ushort4*)(op + (size_t)(dg * 4 + i) * (NH*N_)) = r4;
    }
}

// ---------------------------------------------------------------------------
// Convert projection weights f32 -> bf16 (512x512).
// ---------------------------------------------------------------------------
__global__ __launch_bounds__(256) void wconv_kernel(
    const float* __restrict__ w, bf16* __restrict__ wb)
{
    int i = blockIdx.x * 256 + threadIdx.x;   // 262144 total
    wb[i] = f2bf(w[i]);
}

// ---------------------------------------------------------------------------
// MFMA projection, LDS-staged (m97 structure + T2 swizzle):
//   out[b0+b_l][co][n] = sum_c Wb[co][c]*A[b_l][n][c] + pb[co]
// ---------------------------------------------------------------------------
__global__ __launch_bounds__(256) void proj_mfma_kernel(
    const bf16* __restrict__ A, const bf16* __restrict__ Wb,
    const float* __restrict__ bias, float* __restrict__ out, int b0)
{
    __shared__ bf16 Ws_s[128 * 64];
    __shared__ bf16 As_s[128 * 64];
    int bid = blockIdx.x;                 // HB * 4 * 25
    int b_l = bid / 100; int rem = bid % 100;
    int mt = rem / 25, nt = rem % 25;
    int m0 = mt * 128, n0 = nt * 128;
    int t = threadIdx.x;
    int w = t >> 6, l = t & 63;
    int r16 = l & 15, kg = l >> 4;        // frag row / k-group
    int wr = w >> 1, wc = w & 1;          // wave quadrant
    const bf16* Ab = A + (size_t)b_l * N_ * C_;
    int rsub = l >> 3;                    // row within the 8-row wave chunk
    int colp = ((l & 7) ^ rsub) * 8;      // pre-swizzled k-element offset

    f32x4 acc[4][4];
#pragma unroll
    for (int i = 0; i < 4; ++i)
#pragma unroll
        for (int j = 0; j < 4; ++j) acc[i][j] = (f32x4){0.f, 0.f, 0.f, 0.f};

    for (int k0 = 0; k0 < C_; k0 += 64) {
#pragma unroll
        for (int i = 0; i < 4; ++i) {
            int row = i * 32 + w * 8 + rsub;
            load_lds16(Wb + (size_t)(m0 + row) * C_ + k0 + colp,
                       (char*)Ws_s + i * 4096 + t * 16);
        }
#pragma unroll
        for (int i = 0; i < 4; ++i) {
            int row = i * 32 + w * 8 + rsub;
            int nn = n0 + row; if (nn >= N_) nn = N_ - 1;
            load_lds16(Ab + (size_t)nn * C_ + k0 + colp,
                       (char*)As_s + i * 4096 + t * 16);
        }
        __syncthreads();
#pragma unroll
        for (int ks = 0; ks < 2; ++ks) {
            short8 af[4], bfv[4];
#pragma unroll
            for (int mi = 0; mi < 4; ++mi) {
                int row = wr * 64 + mi * 16 + r16;
                int off = row * 128 + ((ks * 64 + kg * 16) ^ ((row & 7) << 4));
                af[mi] = *(const short8*)((const char*)Ws_s + off);
            }
#pragma unroll
            for (int nj = 0; nj < 4; ++nj) {
                int row = wc * 64 + nj * 16 + r16;
                int off = row * 128 + ((ks * 64 + kg * 16) ^ ((row & 7) << 4));
                bfv[nj] = *(const short8*)((const char*)As_s + off);
            }
#pragma unroll
            for (int mi = 0; mi < 4; ++mi)
#pragma unroll
                for (int nj = 0; nj < 4; ++nj)
                    acc[mi][nj] = __builtin_amdgcn_mfma_f32_16x16x32_bf16(
                        af[mi], bfv[nj], acc[mi][nj], 0, 0, 0);
        }
        __syncthreads();
    }
    float* ob = out + ((size_t)(b0 + b_l) * C_) * N_;
#pragma unroll
    for (int mi = 0; mi < 4; ++mi) {
        int cobase = m0 + wr * 64 + mi * 16 + kg * 4;
#pragma unroll
        for (int r = 0; r < 4; ++r) {
            int co = cobase + r;
            float bi = bias[co];
#pragma unroll
            for (int nj = 0; nj < 4; ++nj) {
                int n = n0 + wc * 64 + nj * 16 + r16;
                if (n < N_) ob[(size_t)co * N_ + n] = acc[mi][nj][r] + bi;
            }
        }
    }
}

extern "C" void kernel_launch(void* const* d_in, const int* in_sizes, int n_in,
                              void* d_out, int out_size, void* d_ws, size_t ws_size,
                              hipStream_t stream) {
    const float* x     = (const float*)d_in[0];
    const float* cw    = (const float*)d_in[1];
    const float* gamma = (const float*)d_in[2];
    const float* beta  = (const float*)d_in[3];
    const float* mean  = (const float*)d_in[4];
    const float* var   = (const float*)d_in[5];
    const float* pw    = (const float*)d_in[6];
    const float* pb    = (const float*)d_in[7];
    float* out = (float*)d_out;

    const size_t QK_B   = (size_t)HB * 2 * C_ * N_ * sizeof(bf16);  // 51,380,224
    const size_t V_B    = (size_t)HB * C_ * N_ * sizeof(bf16);      // 25,690,112
    const size_t PART_B = (size_t)SPLIT * HB * NH * 4096 * 4;       //  7,340,032
    const size_t P_B    = (size_t)HB * NH * 4096 * 4;               //  1,048,576
    const size_t W_B    = (size_t)C_ * C_ * sizeof(bf16);           //    524,288
    char* wsp = (char*)d_ws;
    bool fast = ws_size >= QK_B + V_B + PART_B + P_B + W_B;         // 86.0 MB

    bf16* Wbf = fast ? (bf16*)(wsp + QK_B + V_B + PART_B + P_B)
                     : (bf16*)(wsp + QK_B + PART_B + P_B);
    wconv_kernel<<<(C_ * C_) / 256, 256, 0, stream>>>(pw, Wbf);

    for (int g = 0; g < 2; ++g) {
        int b0 = g * HB;
        if (fast) {
            bf16*  qk   = (bf16*)wsp;
            bf16*  v    = (bf16*)(wsp + QK_B);
            float* part = (float*)(wsp + QK_B + V_B);
            float* PT   = (float*)(wsp + QK_B + V_B + PART_B);
            bf16*  outA = qk;   // reuse q,k region after gram
            conv_bn_kernel<<<HB * C_, 256, 0, stream>>>(
                x, cw, gamma, beta, mean, var, qk, v, b0, 3);
            gram_mfma_kernel<<<HB * NH * SPLIT, 256, 0, stream>>>(qk, part);
            softmax_kernel<<<HB * NH * 64, 64, 0, stream>>>(part, PT);
            pv_kernel<<<HB * NH * 49, 256, 0, stream>>>(v, PT, outA);
            proj_mfma_kernel<<<HB * 4 * 25, 256, 0, stream>>>(outA, Wbf, pb, out, b0);
        } else {
            bf16*  qk   = (bf16*)wsp;
            float* part = (float*)(wsp + QK_B);
            float* PT   = (float*)(wsp + QK_B + PART_B);
            bf16*  v    = qk;                       // reuse after gram
            bf16*  outA = (bf16*)(wsp + V_B);       // second half of qk region
            conv_bn_kernel<<<HB * C_, 256, 0, stream>>>(
                x, cw, gamma, beta, mean, var, qk, (bf16*)nullptr, b0, 1);
            gram_mfma_kernel<<<HB * NH * SPLIT, 256, 0, stream>>>(qk, part);
            softmax_kernel<<<HB * NH * 64, 64, 0, stream>>>(part, PT);
            conv_bn_kernel<<<HB * C_, 256, 0, stream>>>(
                x, cw, gamma, beta, mean, var, (bf16*)nullptr, v, b0, 2);
            pv_kernel<<<HB * NH * 49, 256, 0, stream>>>(v, PT, outA);
            proj_mfma_kernel<<<HB * 4 * 25, 256, 0, stream>>>(outA, Wbf, pb, out, b0);
        }
    }
}

// Round 9
// 219.720 us; speedup vs baseline: 3.6427x; 1.1546x over previous
//
#include <hip/hip_runtime.h>
#include <math.h>

#define B_ 16
#define C_ 512
#define H_ 56
#define W_ 56
#define N_ 3136          // H_*W_ = 49*64
#define NH 8
#define HD 64
#define SPLIT 7          // n-split for gram; 3136/7 = 448

typedef unsigned short bf16;
typedef __attribute__((ext_vector_type(8))) short short8;
typedef __attribute__((ext_vector_type(4))) float f32x4;

__device__ inline float bf2f(unsigned short u) {
    union { unsigned int i; float f; } v; v.i = ((unsigned int)u) << 16; return v.f;
}
__device__ inline unsigned short f2bf(float f) {
    union { float f; unsigned int i; } v; v.f = f;
    unsigned int r = v.i + 0x7fffu + ((v.i >> 16) & 1u);
    return (unsigned short)(r >> 16);
}

// async global->LDS, 16B per lane, linear dest (wave-uniform base + lane*16)
__device__ inline void load_lds16(const void* g, void* l) {
    __builtin_amdgcn_global_load_lds(
        (const __attribute__((address_space(1))) void*)g,
        (__attribute__((address_space(3))) void*)l, 16, 0, 0);
}

// ---------------------------------------------------------------------------
// Depthwise 3x3 conv + BN. Block = (b_l, ic); filter/BN consts block-uniform.
// 448 threads; thread t < 392 owns one 8-wide group: yy = t/7, xx0 = (t%7)*8,
// n0 = 8t (contiguous across wave -> coalesced 16B stores). Always writes
// q,k -> qkdst[(b_l*2+s)*C+c][n] and v -> vdst[b_l*C+c][n].
// ---------------------------------------------------------------------------
__global__ __launch_bounds__(448) void conv_bn_kernel(
    const float* __restrict__ x, const float* __restrict__ cw,
    const float* __restrict__ gamma, const float* __restrict__ beta,
    const float* __restrict__ mean, const float* __restrict__ var,
    bf16* __restrict__ qkdst, bf16* __restrict__ vdst, int b0)
{
    int bid = blockIdx.x;                 // nb*C_
    int ic = bid & 511; int b_l = bid >> 9;
    int b = b0 + b_l;
    const float* xin = x + ((size_t)b * C_ + ic) * N_;

    float w9[3][9], inv3[3], bias3[3];
#pragma unroll
    for (int t = 0; t < 3; ++t) {
        int o = ic * 3 + t;
#pragma unroll
        for (int k = 0; k < 9; ++k) w9[t][k] = cw[o * 9 + k];
        float iv = gamma[o] * rsqrtf(var[o] + 1e-5f);
        inv3[t] = iv;
        bias3[t] = fmaf(-mean[o], iv, beta[o]);
    }

    int t = threadIdx.x;
    if (t < 392) {
        int yy = t / 7;
        int xx0 = (t - yy * 7) * 8;
        int n0 = t * 8;                   // == yy*56 + xx0
        float vin[3][10];
#pragma unroll
        for (int dy = 0; dy < 3; ++dy) {
            int y2 = yy + dy - 1;
            bool rowok = (y2 >= 0) && (y2 < H_);
            const float* rp = xin + y2 * W_ + xx0;
            if (rowok) {
                float4 a = *(const float4*)rp;
                float4 c4 = *(const float4*)(rp + 4);
                vin[dy][1] = a.x;  vin[dy][2] = a.y;  vin[dy][3] = a.z;  vin[dy][4] = a.w;
                vin[dy][5] = c4.x; vin[dy][6] = c4.y; vin[dy][7] = c4.z; vin[dy][8] = c4.w;
                vin[dy][0] = (xx0 > 0)  ? rp[-1] : 0.f;
                vin[dy][9] = (xx0 < 48) ? rp[8]  : 0.f;
            } else {
#pragma unroll
                for (int j = 0; j < 10; ++j) vin[dy][j] = 0.f;
            }
        }
#pragma unroll
        for (int ft = 0; ft < 3; ++ft) {
            int o = ic * 3 + ft;          // uniform
            int s = o >> 9;               // uniform
            int c = o & 511;
            short8 r8;
#pragma unroll
            for (int j = 0; j < 8; ++j) {
                float acc = 0.f;
#pragma unroll
                for (int ky = 0; ky < 3; ++ky)
#pragma unroll
                    for (int kx = 0; kx < 3; ++kx)
                        acc = fmaf(vin[ky][j + kx], w9[ft][ky*3+kx], acc);
                r8[j] = (short)f2bf(fmaf(acc, inv3[ft], bias3[ft]));
            }
            bf16* dst = (s < 2)
                ? qkdst + (((size_t)b_l * 2 + s) * C_ + c) * N_
                : vdst + ((size_t)b_l * C_ + c) * N_;
            *(short8*)(dst + n0) = r8;
        }
    }
}

// ---------------------------------------------------------------------------
// Gram partials via MFMA (T2 swizzle + gload_lds):
//   part[s][bh][d*64+e] = sum_{n in split s} q[d,n]*k[e,n]
// ---------------------------------------------------------------------------
__global__ __launch_bounds__(256) void gram_mfma_kernel(
    const bf16* __restrict__ qk, float* __restrict__ part, int bhTot)
{
    __shared__ bf16 qs[64 * 64];
    __shared__ bf16 ks[64 * 64];
    int bid = blockIdx.x;                 // bhTot*SPLIT
    int s = bid % SPLIT; int bh = bid / SPLIT;
    int h = bh % NH; int b_l = bh / NH;
    const bf16* qp = qk + (((size_t)b_l * 2 + 0) * C_ + h * HD) * N_;
    const bf16* kp = qk + (((size_t)b_l * 2 + 1) * C_ + h * HD) * N_;
    int t = threadIdx.x;
    int w = t >> 6, l = t & 63;
    int r16 = l & 15, kg = l >> 4;
    int wr = w >> 1, wc = w & 1;
    int rsub = l >> 3;
    int colp = ((l & 7) ^ rsub) * 8;      // pre-swizzled n-element offset
    int n0 = s * (N_ / SPLIT);

    f32x4 acc[2][2];
#pragma unroll
    for (int i = 0; i < 2; ++i)
#pragma unroll
        for (int j = 0; j < 2; ++j) acc[i][j] = (f32x4){0.f, 0.f, 0.f, 0.f};

    for (int nc = 0; nc < N_ / SPLIT; nc += 64) {
        int nb = n0 + nc;
#pragma unroll
        for (int i = 0; i < 2; ++i) {
            int row = i * 32 + w * 8 + rsub;
            load_lds16(qp + (size_t)row * N_ + nb + colp, (char*)qs + i * 4096 + t * 16);
            load_lds16(kp + (size_t)row * N_ + nb + colp, (char*)ks + i * 4096 + t * 16);
        }
        __syncthreads();
#pragma unroll
        for (int ksb = 0; ksb < 2; ++ksb) {
            short8 af[2], bfv[2];
#pragma unroll
            for (int mi = 0; mi < 2; ++mi) {
                int row = wr * 32 + mi * 16 + r16;
                int off = row * 128 + ((ksb * 64 + kg * 16) ^ ((row & 7) << 4));
                af[mi] = *(const short8*)((const char*)qs + off);
            }
#pragma unroll
            for (int nj = 0; nj < 2; ++nj) {
                int row = wc * 32 + nj * 16 + r16;
                int off = row * 128 + ((ksb * 64 + kg * 16) ^ ((row & 7) << 4));
                bfv[nj] = *(const short8*)((const char*)ks + off);
            }
#pragma unroll
            for (int mi = 0; mi < 2; ++mi)
#pragma unroll
                for (int nj = 0; nj < 2; ++nj)
                    acc[mi][nj] = __builtin_amdgcn_mfma_f32_16x16x32_bf16(
                        af[mi], bfv[nj], acc[mi][nj], 0, 0, 0);
        }
        __syncthreads();
    }
    float* pp = part + ((size_t)s * bhTot + bh) * 4096;
#pragma unroll
    for (int mi = 0; mi < 2; ++mi)
#pragma unroll
        for (int nj = 0; nj < 2; ++nj) {
            int e = wc * 32 + nj * 16 + r16;
#pragma unroll
            for (int r = 0; r < 4; ++r) {
                int d = wr * 32 + mi * 16 + kg * 4 + r;
                pp[d * 64 + e] = acc[mi][nj][r];
            }
        }
}

// ---------------------------------------------------------------------------
// Reduce partials, scale, softmax over e. One wave per (bh,d) row.
// Writes P TRANSPOSED: PT[bh][e*64+d].
// ---------------------------------------------------------------------------
__global__ __launch_bounds__(64) void softmax_kernel(
    const float* __restrict__ part, float* __restrict__ PT, int bhTot)
{
    int row = blockIdx.x;                 // bh*64 + d
    int e = threadIdx.x;
    size_t base = (size_t)row * 64 + e;
    float val = 0.f;
#pragma unroll
    for (int s = 0; s < SPLIT; ++s) val += part[(size_t)s * bhTot * 4096 + base];
    val *= 0.125f;                        // hd^-0.5
    float m = val;
#pragma unroll
    for (int off = 32; off > 0; off >>= 1) m = fmaxf(m, __shfl_xor(m, off));
    float ex = expf(val - m);
    float sum = ex;
#pragma unroll
    for (int off = 32; off > 0; off >>= 1) sum += __shfl_xor(sum, off);
    PT[(size_t)(row >> 6) * 4096 + (size_t)e * 64 + (row & 63)] = ex / sum;
}

// ---------------------------------------------------------------------------
// outA[b_l][d][h][n] = sum_e PT[e][d] * v[b_l][h*64+e][n]   (bf16 out)
// ---------------------------------------------------------------------------
__global__ __launch_bounds__(256) void pv_kernel(
    const bf16* __restrict__ v, const float* __restrict__ PT,
    bf16* __restrict__ outA)
{
    __shared__ float pts[4096];           // PT[e][d] 16KB
    __shared__ bf16 vs[64 * 64];          // vs[e][n] 8KB
    int bid = blockIdx.x;                 // bhTot*49
    int nt = bid % 49; int bh = bid / 49;
    int h = bh % NH, b_l = bh / NH;
    int t = threadIdx.x;
    const float* ptg = PT + (size_t)bh * 4096;
#pragma unroll
    for (int i = 0; i < 4; ++i)
        load_lds16(ptg + i * 1024 + t * 4, (char*)pts + i * 4096 + t * 16);
    const bf16* vb = v + ((size_t)b_l * C_ + h * HD) * N_ + nt * 64;
#pragma unroll
    for (int i = 0; i < 2; ++i) {
        int row = i * 32 + (t >> 3);
        load_lds16(vb + (size_t)row * N_ + (t & 7) * 8, (char*)vs + i * 4096 + t * 16);
    }
    __syncthreads();

    int ng = t & 15, dg = t >> 4;         // n0 = ng*4, d0 = dg*4
    float acc[4][4] = {};
#pragma unroll 16
    for (int e = 0; e < 64; ++e) {
        float4 p = *(const float4*)&pts[e * 64 + dg * 4];
        ushort4 vv = *(const ushort4*)&vs[e * 64 + ng * 4];
        float v0 = bf2f(vv.x), v1 = bf2f(vv.y), v2 = bf2f(vv.z), v3 = bf2f(vv.w);
        float p4[4] = {p.x, p.y, p.z, p.w};
#pragma unroll
        for (int i = 0; i < 4; ++i) {
            acc[i][0] = fmaf(p4[i], v0, acc[i][0]);
            acc[i][1] = fmaf(p4[i], v1, acc[i][1]);
            acc[i][2] = fmaf(p4[i], v2, acc[i][2]);
            acc[i][3] = fmaf(p4[i], v3, acc[i][3]);
        }
    }
    bf16* op = outA + (size_t)b_l * (C_*N_) + (size_t)h * N_ + nt * 64 + ng * 4;
#pragma unroll
    for (int i = 0; i < 4; ++i) {
        ushort4 r4;
        unsigned short* rr = (unsigned short*)&r4;
        rr[0] = f2bf(acc[i][0]); rr[1] = f2bf(acc[i][1]);
        rr[2] = f2bf(acc[i][2]); rr[3] = f2bf(acc[i][3]);
        *(ushort4*)(op + (size_t)(dg * 4 + i) * (NH*N_)) = r4;
    }
}

// ---------------------------------------------------------------------------
// Convert projection weights f32 -> bf16 (512x512).
// ---------------------------------------------------------------------------
__global__ __launch_bounds__(256) void wconv_kernel(
    const float* __restrict__ w, bf16* __restrict__ wb)
{
    int i = blockIdx.x * 256 + threadIdx.x;   // 262144 total
    wb[i] = f2bf(w[i]);
}

// ---------------------------------------------------------------------------
// MFMA projection, LDS-staged (m97 structure + T2 swizzle):
//   out[b0+b_l][co][n] = sum_c Wb[co][c]*A[b_l][n][c] + pb[co]
// ---------------------------------------------------------------------------
__global__ __launch_bounds__(256) void proj_mfma_kernel(
    const bf16* __restrict__ A, const bf16* __restrict__ Wb,
    const float* __restrict__ bias, float* __restrict__ out, int b0)
{
    __shared__ bf16 Ws_s[128 * 64];
    __shared__ bf16 As_s[128 * 64];
    int bid = blockIdx.x;                 // nb * 4 * 25
    int b_l = bid / 100; int rem = bid % 100;
    int mt = rem / 25, nt = rem % 25;
    int m0 = mt * 128, n0 = nt * 128;
    int t = threadIdx.x;
    int w = t >> 6, l = t & 63;
    int r16 = l & 15, kg = l >> 4;        // frag row / k-group
    int wr = w >> 1, wc = w & 1;          // wave quadrant
    const bf16* Ab = A + (size_t)b_l * N_ * C_;
    int rsub = l >> 3;                    // row within the 8-row wave chunk
    int colp = ((l & 7) ^ rsub) * 8;      // pre-swizzled k-element offset

    f32x4 acc[4][4];
#pragma unroll
    for (int i = 0; i < 4; ++i)
#pragma unroll
        for (int j = 0; j < 4; ++j) acc[i][j] = (f32x4){0.f, 0.f, 0.f, 0.f};

    for (int k0 = 0; k0 < C_; k0 += 64) {
#pragma unroll
        for (int i = 0; i < 4; ++i) {
            int row = i * 32 + w * 8 + rsub;
            load_lds16(Wb + (size_t)(m0 + row) * C_ + k0 + colp,
                       (char*)Ws_s + i * 4096 + t * 16);
        }
#pragma unroll
        for (int i = 0; i < 4; ++i) {
            int row = i * 32 + w * 8 + rsub;
            int nn = n0 + row; if (nn >= N_) nn = N_ - 1;
            load_lds16(Ab + (size_t)nn * C_ + k0 + colp,
                       (char*)As_s + i * 4096 + t * 16);
        }
        __syncthreads();
#pragma unroll
        for (int ks = 0; ks < 2; ++ks) {
            short8 af[4], bfv[4];
#pragma unroll
            for (int mi = 0; mi < 4; ++mi) {
                int row = wr * 64 + mi * 16 + r16;
                int off = row * 128 + ((ks * 64 + kg * 16) ^ ((row & 7) << 4));
                af[mi] = *(const short8*)((const char*)Ws_s + off);
            }
#pragma unroll
            for (int nj = 0; nj < 4; ++nj) {
                int row = wc * 64 + nj * 16 + r16;
                int off = row * 128 + ((ks * 64 + kg * 16) ^ ((row & 7) << 4));
                bfv[nj] = *(const short8*)((const char*)As_s + off);
            }
#pragma unroll
            for (int mi = 0; mi < 4; ++mi)
#pragma unroll
                for (int nj = 0; nj < 4; ++nj)
                    acc[mi][nj] = __builtin_amdgcn_mfma_f32_16x16x32_bf16(
                        af[mi], bfv[nj], acc[mi][nj], 0, 0, 0);
        }
        __syncthreads();
    }
    float* ob = out + ((size_t)(b0 + b_l) * C_) * N_;
#pragma unroll
    for (int mi = 0; mi < 4; ++mi) {
        int cobase = m0 + wr * 64 + mi * 16 + kg * 4;
#pragma unroll
        for (int r = 0; r < 4; ++r) {
            int co = cobase + r;
            float bi = bias[co];
#pragma unroll
            for (int nj = 0; nj < 4; ++nj) {
                int n = n0 + wc * 64 + nj * 16 + r16;
                if (n < N_) ob[(size_t)co * N_ + n] = acc[mi][nj][r] + bi;
            }
        }
    }
}

extern "C" void kernel_launch(void* const* d_in, const int* in_sizes, int n_in,
                              void* d_out, int out_size, void* d_ws, size_t ws_size,
                              hipStream_t stream) {
    const float* x     = (const float*)d_in[0];
    const float* cw    = (const float*)d_in[1];
    const float* gamma = (const float*)d_in[2];
    const float* beta  = (const float*)d_in[3];
    const float* mean  = (const float*)d_in[4];
    const float* var   = (const float*)d_in[5];
    const float* pw    = (const float*)d_in[6];
    const float* pb    = (const float*)d_in[7];
    float* out = (float*)d_out;
    char* wsp = (char*)d_ws;

    const size_t W_B = (size_t)C_ * C_ * sizeof(bf16);              // 524,288

    // Single-pass (all 16 batches) if workspace allows; else two passes of 8.
    size_t qk16   = (size_t)16 * 2 * C_ * N_ * sizeof(bf16);        // 102.8 MB
    size_t v16    = (size_t)16 * C_ * N_ * sizeof(bf16);            //  51.4 MB
    size_t part16 = (size_t)SPLIT * 16 * NH * 4096 * 4;             //  14.7 MB
    size_t pt16   = (size_t)16 * NH * 4096 * 4;                     //   2.1 MB

    int nbs[2]; int ngroups;
    if (ws_size >= qk16 + v16 + part16 + pt16 + W_B) {
        ngroups = 1; nbs[0] = 16;
    } else {
        ngroups = 2; nbs[0] = 8; nbs[1] = 8;
    }

    int b0 = 0;
    for (int gi = 0; gi < ngroups; ++gi) {
        int nb = nbs[gi];
        size_t QK_B   = (size_t)nb * 2 * C_ * N_ * sizeof(bf16);
        size_t V_B    = (size_t)nb * C_ * N_ * sizeof(bf16);
        size_t PART_B = (size_t)SPLIT * nb * NH * 4096 * 4;
        size_t PT_B   = (size_t)nb * NH * 4096 * 4;
        bf16*  qk   = (bf16*)wsp;
        bf16*  v    = (bf16*)(wsp + QK_B);
        float* part = (float*)(wsp + QK_B + V_B);
        float* PT   = (float*)(wsp + QK_B + V_B + PART_B);
        bf16*  Wbf  = (bf16*)(wsp + QK_B + V_B + PART_B + PT_B);
        bf16*  outA = qk;                  // reuse q,k region after gram
        int bhTot = nb * NH;

        if (gi == 0)
            wconv_kernel<<<(C_ * C_) / 256, 256, 0, stream>>>(pw, Wbf);

        conv_bn_kernel<<<nb * C_, 448, 0, stream>>>(
            x, cw, gamma, beta, mean, var, qk, v, b0);
        gram_mfma_kernel<<<bhTot * SPLIT, 256, 0, stream>>>(qk, part, bhTot);
        softmax_kernel<<<bhTot * 64, 64, 0, stream>>>(part, PT, bhTot);
        pv_kernel<<<bhTot * 49, 256, 0, stream>>>(v, PT, outA);
        proj_mfma_kernel<<<nb * 4 * 25, 256, 0, stream>>>(outA, Wbf, pb, out, b0);
        b0 += nb;
    }
}

// Round 10
// 216.008 us; speedup vs baseline: 3.7053x; 1.0172x over previous
//
#include <hip/hip_runtime.h>
#include <math.h>

#define B_ 16
#define C_ 512
#define H_ 56
#define W_ 56
#define N_ 3136          // H_*W_ = 49*64
#define NH 8
#define HD 64
#define SPLIT 7          // n-split for gram; 3136/7 = 448

typedef unsigned short bf16;
typedef __attribute__((ext_vector_type(8))) short short8;
typedef __attribute__((ext_vector_type(4))) float f32x4;

__device__ inline float bf2f(unsigned short u) {
    union { unsigned int i; float f; } v; v.i = ((unsigned int)u) << 16; return v.f;
}
__device__ inline unsigned short f2bf(float f) {
    union { float f; unsigned int i; } v; v.f = f;
    unsigned int r = v.i + 0x7fffu + ((v.i >> 16) & 1u);
    return (unsigned short)(r >> 16);
}

// async global->LDS, 16B per lane, linear dest (wave-uniform base + lane*16)
__device__ inline void load_lds16(const void* g, void* l) {
    __builtin_amdgcn_global_load_lds(
        (const __attribute__((address_space(1))) void*)g,
        (__attribute__((address_space(3))) void*)l, 16, 0, 0);
}

// ---------------------------------------------------------------------------
// Depthwise 3x3 conv + BN. Block = (b_l, ic); filter/BN consts block-uniform.
// 448 threads; thread t < 392 owns one 8-wide group; n0 = 8t (coalesced).
// ---------------------------------------------------------------------------
__global__ __launch_bounds__(448) void conv_bn_kernel(
    const float* __restrict__ x, const float* __restrict__ cw,
    const float* __restrict__ gamma, const float* __restrict__ beta,
    const float* __restrict__ mean, const float* __restrict__ var,
    bf16* __restrict__ qkdst, bf16* __restrict__ vdst, int b0)
{
    int bid = blockIdx.x;                 // nb*C_
    int ic = bid & 511; int b_l = bid >> 9;
    int b = b0 + b_l;
    const float* xin = x + ((size_t)b * C_ + ic) * N_;

    float w9[3][9], inv3[3], bias3[3];
#pragma unroll
    for (int t = 0; t < 3; ++t) {
        int o = ic * 3 + t;
#pragma unroll
        for (int k = 0; k < 9; ++k) w9[t][k] = cw[o * 9 + k];
        float iv = gamma[o] * rsqrtf(var[o] + 1e-5f);
        inv3[t] = iv;
        bias3[t] = fmaf(-mean[o], iv, beta[o]);
    }

    int t = threadIdx.x;
    if (t < 392) {
        int yy = t / 7;
        int xx0 = (t - yy * 7) * 8;
        int n0 = t * 8;                   // == yy*56 + xx0
        float vin[3][10];
#pragma unroll
        for (int dy = 0; dy < 3; ++dy) {
            int y2 = yy + dy - 1;
            bool rowok = (y2 >= 0) && (y2 < H_);
            const float* rp = xin + y2 * W_ + xx0;
            if (rowok) {
                float4 a = *(const float4*)rp;
                float4 c4 = *(const float4*)(rp + 4);
                vin[dy][1] = a.x;  vin[dy][2] = a.y;  vin[dy][3] = a.z;  vin[dy][4] = a.w;
                vin[dy][5] = c4.x; vin[dy][6] = c4.y; vin[dy][7] = c4.z; vin[dy][8] = c4.w;
                vin[dy][0] = (xx0 > 0)  ? rp[-1] : 0.f;
                vin[dy][9] = (xx0 < 48) ? rp[8]  : 0.f;
            } else {
#pragma unroll
                for (int j = 0; j < 10; ++j) vin[dy][j] = 0.f;
            }
        }
#pragma unroll
        for (int ft = 0; ft < 3; ++ft) {
            int o = ic * 3 + ft;          // uniform
            int s = o >> 9;               // uniform
            int c = o & 511;
            short8 r8;
#pragma unroll
            for (int j = 0; j < 8; ++j) {
                float acc = 0.f;
#pragma unroll
                for (int ky = 0; ky < 3; ++ky)
#pragma unroll
                    for (int kx = 0; kx < 3; ++kx)
                        acc = fmaf(vin[ky][j + kx], w9[ft][ky*3+kx], acc);
                r8[j] = (short)f2bf(fmaf(acc, inv3[ft], bias3[ft]));
            }
            bf16* dst = (s < 2)
                ? qkdst + (((size_t)b_l * 2 + s) * C_ + c) * N_
                : vdst + ((size_t)b_l * C_ + c) * N_;
            *(short8*)(dst + n0) = r8;
        }
    }
}

// ---------------------------------------------------------------------------
// Gram partials via MFMA (T2 swizzle + gload_lds):
//   part[s][bh][d*64+e] = sum_{n in split s} q[d,n]*k[e,n]
// ---------------------------------------------------------------------------
__global__ __launch_bounds__(256) void gram_mfma_kernel(
    const bf16* __restrict__ qk, float* __restrict__ part, int bhTot)
{
    __shared__ bf16 qs[64 * 64];
    __shared__ bf16 ks[64 * 64];
    int bid = blockIdx.x;                 // bhTot*SPLIT
    int s = bid % SPLIT; int bh = bid / SPLIT;
    int h = bh % NH; int b_l = bh / NH;
    const bf16* qp = qk + (((size_t)b_l * 2 + 0) * C_ + h * HD) * N_;
    const bf16* kp = qk + (((size_t)b_l * 2 + 1) * C_ + h * HD) * N_;
    int t = threadIdx.x;
    int w = t >> 6, l = t & 63;
    int r16 = l & 15, kg = l >> 4;
    int wr = w >> 1, wc = w & 1;
    int rsub = l >> 3;
    int colp = ((l & 7) ^ rsub) * 8;      // pre-swizzled n-element offset
    int n0 = s * (N_ / SPLIT);

    f32x4 acc[2][2];
#pragma unroll
    for (int i = 0; i < 2; ++i)
#pragma unroll
        for (int j = 0; j < 2; ++j) acc[i][j] = (f32x4){0.f, 0.f, 0.f, 0.f};

    for (int nc = 0; nc < N_ / SPLIT; nc += 64) {
        int nb = n0 + nc;
#pragma unroll
        for (int i = 0; i < 2; ++i) {
            int row = i * 32 + w * 8 + rsub;
            load_lds16(qp + (size_t)row * N_ + nb + colp, (char*)qs + i * 4096 + t * 16);
            load_lds16(kp + (size_t)row * N_ + nb + colp, (char*)ks + i * 4096 + t * 16);
        }
        __syncthreads();
#pragma unroll
        for (int ksb = 0; ksb < 2; ++ksb) {
            short8 af[2], bfv[2];
#pragma unroll
            for (int mi = 0; mi < 2; ++mi) {
                int row = wr * 32 + mi * 16 + r16;
                int off = row * 128 + ((ksb * 64 + kg * 16) ^ ((row & 7) << 4));
                af[mi] = *(const short8*)((const char*)qs + off);
            }
#pragma unroll
            for (int nj = 0; nj < 2; ++nj) {
                int row = wc * 32 + nj * 16 + r16;
                int off = row * 128 + ((ksb * 64 + kg * 16) ^ ((row & 7) << 4));
                bfv[nj] = *(const short8*)((const char*)ks + off);
            }
#pragma unroll
            for (int mi = 0; mi < 2; ++mi)
#pragma unroll
                for (int nj = 0; nj < 2; ++nj)
                    acc[mi][nj] = __builtin_amdgcn_mfma_f32_16x16x32_bf16(
                        af[mi], bfv[nj], acc[mi][nj], 0, 0, 0);
        }
        __syncthreads();
    }
    float* pp = part + ((size_t)s * bhTot + bh) * 4096;
#pragma unroll
    for (int mi = 0; mi < 2; ++mi)
#pragma unroll
        for (int nj = 0; nj < 2; ++nj) {
            int e = wc * 32 + nj * 16 + r16;
#pragma unroll
            for (int r = 0; r < 4; ++r) {
                int d = wr * 32 + mi * 16 + kg * 4 + r;
                pp[d * 64 + e] = acc[mi][nj][r];
            }
        }
}

// ---------------------------------------------------------------------------
// Reduce partials, scale, softmax over e. One wave per (bh,d) row.
// Writes P TRANSPOSED: PT[bh][e*64+d].
// ---------------------------------------------------------------------------
__global__ __launch_bounds__(64) void softmax_kernel(
    const float* __restrict__ part, float* __restrict__ PT, int bhTot)
{
    int row = blockIdx.x;                 // bh*64 + d
    int e = threadIdx.x;
    size_t base = (size_t)row * 64 + e;
    float val = 0.f;
#pragma unroll
    for (int s = 0; s < SPLIT; ++s) val += part[(size_t)s * bhTot * 4096 + base];
    val *= 0.125f;                        // hd^-0.5
    float m = val;
#pragma unroll
    for (int off = 32; off > 0; off >>= 1) m = fmaxf(m, __shfl_xor(m, off));
    float ex = expf(val - m);
    float sum = ex;
#pragma unroll
    for (int off = 32; off > 0; off >>= 1) sum += __shfl_xor(sum, off);
    PT[(size_t)(row >> 6) * 4096 + (size_t)e * 64 + (row & 63)] = ex / sum;
}

// ---------------------------------------------------------------------------
// outA[b_l][d][h][n] = sum_e PT[e][d] * v[b_l][h*64+e][n]   (bf16 out)
// ---------------------------------------------------------------------------
__global__ __launch_bounds__(256) void pv_kernel(
    const bf16* __restrict__ v, const float* __restrict__ PT,
    bf16* __restrict__ outA)
{
    __shared__ float pts[4096];           // PT[e][d] 16KB
    __shared__ bf16 vs[64 * 64];          // vs[e][n] 8KB
    int bid = blockIdx.x;                 // bhTot*49
    int nt = bid % 49; int bh = bid / 49;
    int h = bh % NH, b_l = bh / NH;
    int t = threadIdx.x;
    const float* ptg = PT + (size_t)bh * 4096;
#pragma unroll
    for (int i = 0; i < 4; ++i)
        load_lds16(ptg + i * 1024 + t * 4, (char*)pts + i * 4096 + t * 16);
    const bf16* vb = v + ((size_t)b_l * C_ + h * HD) * N_ + nt * 64;
#pragma unroll
    for (int i = 0; i < 2; ++i) {
        int row = i * 32 + (t >> 3);
        load_lds16(vb + (size_t)row * N_ + (t & 7) * 8, (char*)vs + i * 4096 + t * 16);
    }
    __syncthreads();

    int ng = t & 15, dg = t >> 4;         // n0 = ng*4, d0 = dg*4
    float acc[4][4] = {};
#pragma unroll 16
    for (int e = 0; e < 64; ++e) {
        float4 p = *(const float4*)&pts[e * 64 + dg * 4];
        ushort4 vv = *(const ushort4*)&vs[e * 64 + ng * 4];
        float v0 = bf2f(vv.x), v1 = bf2f(vv.y), v2 = bf2f(vv.z), v3 = bf2f(vv.w);
        float p4[4] = {p.x, p.y, p.z, p.w};
#pragma unroll
        for (int i = 0; i < 4; ++i) {
            acc[i][0] = fmaf(p4[i], v0, acc[i][0]);
            acc[i][1] = fmaf(p4[i], v1, acc[i][1]);
            acc[i][2] = fmaf(p4[i], v2, acc[i][2]);
            acc[i][3] = fmaf(p4[i], v3, acc[i][3]);
        }
    }
    bf16* op = outA + (size_t)b_l * (C_*N_) + (size_t)h * N_ + nt * 64 + ng * 4;
#pragma unroll
    for (int i = 0; i < 4; ++i) {
        ushort4 r4;
        unsigned short* rr = (unsigned short*)&r4;
        rr[0] = f2bf(acc[i][0]); rr[1] = f2bf(acc[i][1]);
        rr[2] = f2bf(acc[i][2]); rr[3] = f2bf(acc[i][3]);
        *(ushort4*)(op + (size_t)(dg * 4 + i) * (NH*N_)) = r4;
    }
}

// ---------------------------------------------------------------------------
// Convert projection weights f32 -> bf16 (512x512).
// ---------------------------------------------------------------------------
__global__ __launch_bounds__(256) void wconv_kernel(
    const float* __restrict__ w, bf16* __restrict__ wb)
{
    int i = blockIdx.x * 256 + threadIdx.x;   // 262144 total
    wb[i] = f2bf(w[i]);
}

// ---------------------------------------------------------------------------
// MFMA projection, 2-phase double-buffered + XCD-chunked swizzle:
//   out[b0+b_l][co][n] = sum_c Wb[co][c]*A[b_l][n][c] + pb[co]
// Decomposition mt-FASTEST so the 4 blocks sharing an A-panel are contiguous
// in swizzled id -> same XCD -> A fetched from HBM once (was 2x).
// K-loop: prologue-stage, then {stage buf^1 for k+1; compute buf; barrier}.
// ---------------------------------------------------------------------------
__global__ __launch_bounds__(256) void proj_mfma_kernel(
    const bf16* __restrict__ A, const bf16* __restrict__ Wb,
    const float* __restrict__ bias, float* __restrict__ out, int b0, int nwg)
{
    __shared__ bf16 Ws_s[2][128 * 64];
    __shared__ bf16 As_s[2][128 * 64];
    int bid = blockIdx.x;                 // nwg = nb*100, nwg % 8 == 0
    int cpx = nwg >> 3;                   // chunk per XCD (200: % 4 == 0)
    int swz = (bid & 7) * cpx + (bid >> 3);
    int b_l = swz / 100; int rem = swz % 100;
    int nt = rem >> 2, mt = rem & 3;      // mt fastest: A-quad on one XCD
    int m0 = mt * 128, n0 = nt * 128;
    int t = threadIdx.x;
    int w = t >> 6, l = t & 63;
    int r16 = l & 15, kg = l >> 4;        // frag row / k-group
    int wr = w >> 1, wc = w & 1;          // wave quadrant
    const bf16* Ab = A + (size_t)b_l * N_ * C_;
    int rsub = l >> 3;                    // row within the 8-row wave chunk
    int colp = ((l & 7) ^ rsub) * 8;      // pre-swizzled k-element offset

    f32x4 acc[4][4];
#pragma unroll
    for (int i = 0; i < 4; ++i)
#pragma unroll
        for (int j = 0; j < 4; ++j) acc[i][j] = (f32x4){0.f, 0.f, 0.f, 0.f};

#define PROJ_STAGE(BUF, K0)                                                   \
    do {                                                                      \
        _Pragma("unroll")                                                     \
        for (int i = 0; i < 4; ++i) {                                         \
            int row = i * 32 + w * 8 + rsub;                                  \
            load_lds16(Wb + (size_t)(m0 + row) * C_ + (K0) + colp,            \
                       (char*)Ws_s[BUF] + i * 4096 + t * 16);                 \
        }                                                                     \
        _Pragma("unroll")                                                     \
        for (int i = 0; i < 4; ++i) {                                         \
            int row = i * 32 + w * 8 + rsub;                                  \
            int nn = n0 + row; if (nn >= N_) nn = N_ - 1;                     \
            load_lds16(Ab + (size_t)nn * C_ + (K0) + colp,                    \
                       (char*)As_s[BUF] + i * 4096 + t * 16);                 \
        }                                                                     \
    } while (0)

#define PROJ_COMPUTE(BUF)                                                     \
    do {                                                                      \
        _Pragma("unroll")                                                     \
        for (int ks = 0; ks < 2; ++ks) {                                      \
            short8 af[4], bfv[4];                                             \
            _Pragma("unroll")                                                 \
            for (int mi = 0; mi < 4; ++mi) {                                  \
                int row = wr * 64 + mi * 16 + r16;                            \
                int off = row * 128 + ((ks * 64 + kg * 16) ^ ((row & 7) << 4)); \
                af[mi] = *(const short8*)((const char*)Ws_s[BUF] + off);      \
            }                                                                 \
            _Pragma("unroll")                                                 \
            for (int nj = 0; nj < 4; ++nj) {                                  \
                int row = wc * 64 + nj * 16 + r16;                            \
                int off = row * 128 + ((ks * 64 + kg * 16) ^ ((row & 7) << 4)); \
                bfv[nj] = *(const short8*)((const char*)As_s[BUF] + off);     \
            }                                                                 \
            _Pragma("unroll")                                                 \
            for (int mi = 0; mi < 4; ++mi)                                    \
                _Pragma("unroll")                                             \
                for (int nj = 0; nj < 4; ++nj)                                \
                    acc[mi][nj] = __builtin_amdgcn_mfma_f32_16x16x32_bf16(    \
                        af[mi], bfv[nj], acc[mi][nj], 0, 0, 0);               \
        }                                                                     \
    } while (0)

    PROJ_STAGE(0, 0);
    __syncthreads();                      // drain prologue loads
    int cur = 0;
#pragma unroll
    for (int k = 0; k < 7; ++k) {
        PROJ_STAGE(cur ^ 1, (k + 1) * 64);   // next tile in flight...
        PROJ_COMPUTE(cur);                    // ...hidden under current MFMA
        __syncthreads();                      // vmcnt(0)+lgkm(0)+barrier
        cur ^= 1;
    }
    PROJ_COMPUTE(cur);

    float* ob = out + ((size_t)(b0 + b_l) * C_) * N_;
#pragma unroll
    for (int mi = 0; mi < 4; ++mi) {
        int cobase = m0 + wr * 64 + mi * 16 + kg * 4;
#pragma unroll
        for (int r = 0; r < 4; ++r) {
            int co = cobase + r;
            float bi = bias[co];
#pragma unroll
            for (int nj = 0; nj < 4; ++nj) {
                int n = n0 + wc * 64 + nj * 16 + r16;
                if (n < N_) ob[(size_t)co * N_ + n] = acc[mi][nj][r] + bi;
            }
        }
    }
#undef PROJ_STAGE
#undef PROJ_COMPUTE
}

extern "C" void kernel_launch(void* const* d_in, const int* in_sizes, int n_in,
                              void* d_out, int out_size, void* d_ws, size_t ws_size,
                              hipStream_t stream) {
    const float* x     = (const float*)d_in[0];
    const float* cw    = (const float*)d_in[1];
    const float* gamma = (const float*)d_in[2];
    const float* beta  = (const float*)d_in[3];
    const float* mean  = (const float*)d_in[4];
    const float* var   = (const float*)d_in[5];
    const float* pw    = (const float*)d_in[6];
    const float* pb    = (const float*)d_in[7];
    float* out = (float*)d_out;
    char* wsp = (char*)d_ws;

    const size_t W_B = (size_t)C_ * C_ * sizeof(bf16);              // 524,288

    // Single-pass (all 16 batches) if workspace allows; else two passes of 8.
    size_t qk16   = (size_t)16 * 2 * C_ * N_ * sizeof(bf16);        // 102.8 MB
    size_t v16    = (size_t)16 * C_ * N_ * sizeof(bf16);            //  51.4 MB
    size_t part16 = (size_t)SPLIT * 16 * NH * 4096 * 4;             //  14.7 MB
    size_t pt16   = (size_t)16 * NH * 4096 * 4;                     //   2.1 MB

    int nbs[2]; int ngroups;
    if (ws_size >= qk16 + v16 + part16 + pt16 + W_B) {
        ngroups = 1; nbs[0] = 16;
    } else {
        ngroups = 2; nbs[0] = 8; nbs[1] = 8;
    }

    int b0 = 0;
    for (int gi = 0; gi < ngroups; ++gi) {
        int nb = nbs[gi];
        size_t QK_B   = (size_t)nb * 2 * C_ * N_ * sizeof(bf16);
        size_t V_B    = (size_t)nb * C_ * N_ * sizeof(bf16);
        size_t PART_B = (size_t)SPLIT * nb * NH * 4096 * 4;
        size_t PT_B   = (size_t)nb * NH * 4096 * 4;
        bf16*  qk   = (bf16*)wsp;
        bf16*  v    = (bf16*)(wsp + QK_B);
        float* part = (float*)(wsp + QK_B + V_B);
        float* PT   = (float*)(wsp + QK_B + V_B + PART_B);
        bf16*  Wbf  = (bf16*)(wsp + QK_B + V_B + PART_B + PT_B);
        bf16*  outA = qk;                  // reuse q,k region after gram
        int bhTot = nb * NH;

        if (gi == 0)
            wconv_kernel<<<(C_ * C_) / 256, 256, 0, stream>>>(pw, Wbf);

        conv_bn_kernel<<<nb * C_, 448, 0, stream>>>(
            x, cw, gamma, beta, mean, var, qk, v, b0);
        gram_mfma_kernel<<<bhTot * SPLIT, 256, 0, stream>>>(qk, part, bhTot);
        softmax_kernel<<<bhTot * 64, 64, 0, stream>>>(part, PT, bhTot);
        pv_kernel<<<bhTot * 49, 256, 0, stream>>>(v, PT, outA);
        proj_mfma_kernel<<<nb * 4 * 25, 256, 0, stream>>>(outA, Wbf, pb, out, b0, nb * 100);
        b0 += nb;
    }
}